// Round 1
// baseline (1424.908 us; speedup 1.0000x reference)
//
#include <hip/hip_runtime.h>
#include <hip/hip_bf16.h>
#include <math.h>

#define TJ 32

// ---------------- kernel 1: pi/pj = single @ film_W1 halves ----------------
__global__ __launch_bounds__(256) void k_pipj(const float* __restrict__ single,
                                              const float* __restrict__ fW1,
                                              float* __restrict__ pi,
                                              float* __restrict__ pj) {
    const int i = blockIdx.x;
    const int t = threadIdx.x;
    const int sel = t >> 7;      // 0 -> pi, 1 -> pj
    const int c = t & 127;
    const float* srow = single + i * 256;
    const float* w = fW1 + sel * 256 * 128 + c;
    float acc = 0.f;
    for (int k = 0; k < 256; ++k) acc += srow[k] * w[k * 128];
    float* dst = sel ? pj : pi;
    dst[i * 128 + c] = acc;
}

// ------------- kernel 2: fused FiLM -> gamma/beta -> reduction MLP ----------
// block: one i, 32 j's. out[i][j][0:32]
__global__ __launch_bounds__(256) void k_film_red(
    const float* __restrict__ pair,  // [512][512][128]
    const float* __restrict__ pi,    // [512][128]
    const float* __restrict__ pj,    // [512][128]
    const float* __restrict__ fb1,   // [128]
    const float* __restrict__ fW2,   // [128][256]
    const float* __restrict__ fb2,   // [256]
    const float* __restrict__ rW1,   // [128][64]
    const float* __restrict__ rb1,   // [64]
    const float* __restrict__ rW2,   // [64][32]
    const float* __restrict__ rb2,   // [32]
    float* __restrict__ out)         // [512][512][32]
{
    // region A: hs[TJ][129] (16512 B)  then rw1s[64][64] (16384 B)
    __shared__ __align__(16) char bufA[TJ * 129 * 4];
    // region B: w2s[16][256] (16384 B) then p2s[TJ][132] (16896 B)
    __shared__ __align__(16) char bufB[TJ * 132 * 4];
    __shared__ float t1s[TJ][68];
    __shared__ float rw2s[64][32];

    float (*hs)[129]   = reinterpret_cast<float(*)[129]>(bufA);
    float (*rw1s)[64]  = reinterpret_cast<float(*)[64]>(bufA);
    float (*w2s)[256]  = reinterpret_cast<float(*)[256]>(bufB);
    float (*p2s)[132]  = reinterpret_cast<float(*)[132]>(bufB);

    const int t = threadIdx.x;
    const int i = blockIdx.x >> 4;
    const int j0 = (blockIdx.x & 15) * TJ;

    // P0: h tile = relu(pi[i] + pj[j] + b1)
    for (int u = t; u < TJ * 128; u += 256) {
        const int j = u >> 7, k = u & 127;
        float v = pi[i * 128 + k] + pj[(j0 + j) * 128 + k] + fb1[k];
        hs[j][k] = v > 0.f ? v : 0.f;
    }
    for (int u = t; u < 64 * 32; u += 256) rw2s[u >> 5][u & 31] = rW2[u];

    // P1: x = h @ W2 ; thread owns j = ty+8a (a<4), c = tx+32m (m<8)
    const int tx = t & 31, ty = t >> 5;
    float acc[4][8];
#pragma unroll
    for (int a = 0; a < 4; ++a)
#pragma unroll
        for (int m = 0; m < 8; ++m) acc[a][m] = 0.f;

    for (int kc = 0; kc < 8; ++kc) {
        __syncthreads();  // prev chunk consumed (first iter: P0 writes visible)
        for (int u = t; u < 16 * 256; u += 256) {
            const int r = u >> 8, c = u & 255;
            w2s[r][c] = fW2[(kc * 16 + r) * 256 + c];
        }
        __syncthreads();
#pragma unroll 4
        for (int kk = 0; kk < 16; ++kk) {
            const int k = kc * 16 + kk;
            float hv[4];
#pragma unroll
            for (int a = 0; a < 4; ++a) hv[a] = hs[ty + 8 * a][k];
#pragma unroll
            for (int m = 0; m < 8; ++m) {
                const float w = w2s[kk][tx + 32 * m];
#pragma unroll
                for (int a = 0; a < 4; ++a) acc[a][m] += hv[a] * w;
            }
        }
    }
    __syncthreads();   // done reading hs & w2s

    // P2: gamma/beta -> pair2 tile (into region B); stage rw1 chunk0 (region A)
    {
        const float* prow = pair + ((long)i * 512 + j0) * 128;
#pragma unroll
        for (int m = 0; m < 4; ++m) {
            const int c = tx + 32 * m;
            const float b2lo = fb2[c], b2hi = fb2[128 + c];
#pragma unroll
            for (int a = 0; a < 4; ++a) {
                const int j = ty + 8 * a;
                const float xlo = acc[a][m] + b2lo;
                const float xhi = acc[a][m + 4] + b2hi;
                const float g = 1.f + 0.2f * tanhf(xlo);
                const float bb = 0.2f * tanhf(xhi);
                p2s[j][c] = g * prow[j * 128 + c] + bb;
            }
        }
    }
    for (int u = t; u < 64 * 64; u += 256) rw1s[u >> 6][u & 63] = rW1[u];
    __syncthreads();

    // P3: red1 = gelu(pair2 @ rW1 + rb1); thread: d = t&63, j = jb + 4u
    {
        const int d = t & 63;
        const int jb = t >> 6;  // 0..3
        float r1[8];
#pragma unroll
        for (int u = 0; u < 8; ++u) r1[u] = 0.f;
        for (int c = 0; c < 64; ++c) {
            const float w = rw1s[c][d];
#pragma unroll
            for (int u = 0; u < 8; ++u) r1[u] += p2s[jb + 4 * u][c] * w;
        }
        __syncthreads();
        for (int u = t; u < 64 * 64; u += 256) rw1s[u >> 6][u & 63] = rW1[64 * 64 + u];
        __syncthreads();
        for (int c = 0; c < 64; ++c) {
            const float w = rw1s[c][d];
#pragma unroll
            for (int u = 0; u < 8; ++u) r1[u] += p2s[jb + 4 * u][64 + c] * w;
        }
        const float brd = rb1[d];
#pragma unroll
        for (int u = 0; u < 8; ++u) {
            const float x = r1[u] + brd;
            t1s[jb + 4 * u][d] = 0.5f * x * (1.f + erff(x * 0.70710678118654752f));
        }
    }
    __syncthreads();

    // P4: red2: out = t1 @ rW2 + rb2; thread: e = t&31, j = jb2 + 8u
    {
        const int e = t & 31;
        const int jb2 = t >> 5;  // 0..7
        float r2[4];
#pragma unroll
        for (int u = 0; u < 4; ++u) r2[u] = 0.f;
        for (int d = 0; d < 64; ++d) {
            const float w = rw2s[d][e];
#pragma unroll
            for (int u = 0; u < 4; ++u) r2[u] += t1s[jb2 + 8 * u][d] * w;
        }
        const float br = rb2[e];
#pragma unroll
        for (int u = 0; u < 4; ++u)
            out[((long)i * 512 + j0 + jb2 + 8 * u) * 32 + e] = r2[u] + br;
    }
}

// ---------------- kernel 3: windowed MHSA (64 tokens, 2 heads, C=32) --------
__global__ __launch_bounds__(128) void k_attn(
    const float* __restrict__ in,
    float* __restrict__ outbuf,
    const float* __restrict__ qW,  // [32][96]
    const float* __restrict__ qb,  // [96]
    const float* __restrict__ oW,  // [32][32]
    const float* __restrict__ ob,  // [32]
    const int col_pass)
{
    __shared__ float Xs[64][33];
    __shared__ float qWs[32][96];
    __shared__ float qkvs[64][100];
    __shared__ float os[64][33];
    __shared__ float oWs[32][32];
    __shared__ float qbs[96];
    __shared__ float obs[32];

    const int t = threadIdx.x;
    const int r = blockIdx.x >> 3;
    const int w = blockIdx.x & 7;
    long base; int stride;
    if (col_pass) { base = (long)(w * 64) * 512 * 32 + r * 32; stride = 512 * 32; }
    else          { base = ((long)r * 512 + w * 64) * 32;      stride = 32; }

    for (int u = t; u < 64 * 32; u += 128) {
        const int tok = u >> 5, c = u & 31;
        Xs[tok][c] = in[base + (long)tok * stride + c];
    }
    for (int u = t; u < 32 * 96; u += 128) qWs[u / 96][u % 96] = qW[u];
    for (int u = t; u < 32 * 32; u += 128) oWs[u >> 5][u & 31] = oW[u];
    if (t < 96) qbs[t] = qb[t];
    if (t < 32) obs[t] = ob[t];
    __syncthreads();

    // qkv = X @ qW + qb
    for (int u = t; u < 64 * 96; u += 128) {
        const int tok = u / 96, col = u % 96;
        float s = qbs[col];
#pragma unroll
        for (int c = 0; c < 32; ++c) s += Xs[tok][c] * qWs[c][col];
        qkvs[tok][col] = s;
    }
    __syncthreads();

    // per-(q,h) attention, softmax in registers
    {
        const int h = t >> 6, q = t & 63;
        float qv[16];
#pragma unroll
        for (int d = 0; d < 16; ++d) qv[d] = qkvs[q][h * 16 + d];
        float s[64];
        float mx = -1e30f;
        for (int kk = 0; kk < 64; ++kk) {
            float a = 0.f;
#pragma unroll
            for (int d = 0; d < 16; ++d) a += qv[d] * qkvs[kk][32 + h * 16 + d];
            a *= 0.25f;  // hd^-0.5, hd=16
            s[kk] = a;
            mx = fmaxf(mx, a);
        }
        float sum = 0.f;
        for (int kk = 0; kk < 64; ++kk) { s[kk] = expf(s[kk] - mx); sum += s[kk]; }
        const float inv = 1.f / sum;
        float o[16];
#pragma unroll
        for (int d = 0; d < 16; ++d) o[d] = 0.f;
        for (int kk = 0; kk < 64; ++kk) {
            const float a = s[kk];
#pragma unroll
            for (int d = 0; d < 16; ++d) o[d] += a * qkvs[kk][64 + h * 16 + d];
        }
#pragma unroll
        for (int d = 0; d < 16; ++d) os[q][h * 16 + d] = o[d] * inv;
    }
    __syncthreads();

    // out projection
    for (int u = t; u < 64 * 32; u += 128) {
        const int tok = u >> 5, c = u & 31;
        float s = obs[c];
#pragma unroll
        for (int d = 0; d < 32; ++d) s += os[tok][d] * oWs[d][c];
        outbuf[base + (long)tok * stride + c] = s;
    }
}

// ---------------- kernel 4: head MLP + sigmoid ------------------------------
__global__ __launch_bounds__(256) void k_head(
    const float* __restrict__ p3,   // [512][512][32]
    const float* __restrict__ hW1,  // [32][64]
    const float* __restrict__ hb1,  // [64]
    const float* __restrict__ hW2,  // [64][1]
    const float* __restrict__ hb2,  // [1]
    float* __restrict__ outp)       // [512*512]
{
    __shared__ float w1s[32][64];
    __shared__ float w2s[64];
    __shared__ float b1s[64];
    const int t = threadIdx.x;
    for (int u = t; u < 2048; u += 256) w1s[u >> 6][u & 63] = hW1[u];
    if (t < 64) { w2s[t] = hW2[t]; b1s[t] = hb1[t]; }
    __syncthreads();
    const float hb2v = hb2[0];

    const long idx = (long)blockIdx.x * 256 + t;
    const float4* xp = (const float4*)(p3 + idx * 32);
    float x[32];
#pragma unroll
    for (int q4 = 0; q4 < 8; ++q4) {
        const float4 v = xp[q4];
        x[q4 * 4 + 0] = v.x; x[q4 * 4 + 1] = v.y;
        x[q4 * 4 + 2] = v.z; x[q4 * 4 + 3] = v.w;
    }
    float logit = hb2v;
    for (int d = 0; d < 64; ++d) {
        float s = b1s[d];
#pragma unroll
        for (int c = 0; c < 32; ++c) s += x[c] * w1s[c][d];
        s = s > 0.f ? s : 0.f;
        logit += s * w2s[d];
    }
    outp[idx] = 1.f / (1.f + expf(-logit));
}

// ---------------------------------------------------------------------------
extern "C" void kernel_launch(void* const* d_in, const int* in_sizes, int n_in,
                              void* d_out, int out_size, void* d_ws, size_t ws_size,
                              hipStream_t stream) {
    (void)in_sizes; (void)n_in; (void)out_size; (void)ws_size;
    const float* single = (const float*)d_in[0];
    const float* pair   = (const float*)d_in[1];
    const float* fW1 = (const float*)d_in[2];
    const float* fb1 = (const float*)d_in[3];
    const float* fW2 = (const float*)d_in[4];
    const float* fb2 = (const float*)d_in[5];
    const float* rW1 = (const float*)d_in[6];
    const float* rb1 = (const float*)d_in[7];
    const float* rW2 = (const float*)d_in[8];
    const float* rb2 = (const float*)d_in[9];
    const float* qW  = (const float*)d_in[10];
    const float* qb  = (const float*)d_in[11];
    const float* oW  = (const float*)d_in[12];
    const float* ob  = (const float*)d_in[13];
    const float* hW1 = (const float*)d_in[14];
    const float* hb1 = (const float*)d_in[15];
    const float* hW2 = (const float*)d_in[16];
    const float* hb2 = (const float*)d_in[17];
    float* outp = (float*)d_out;

    char* ws = (char*)d_ws;
    float* pi   = (float*)ws;                                   // 256 KB
    float* pj   = (float*)(ws + 256 * 1024);                    // 256 KB
    float* bufA = (float*)(ws + 1024 * 1024);                   // 32 MB
    float* bufB = (float*)(ws + 1024 * 1024 + 33554432);        // 32 MB

    k_pipj<<<512, 256, 0, stream>>>(single, fW1, pi, pj);
    k_film_red<<<8192, 256, 0, stream>>>(pair, pi, pj, fb1, fW2, fb2,
                                         rW1, rb1, rW2, rb2, bufA);
    k_attn<<<4096, 128, 0, stream>>>(bufA, bufB, qW, qb, oW, ob, 0);  // rows (over j)
    k_attn<<<4096, 128, 0, stream>>>(bufB, bufA, qW, qb, oW, ob, 1);  // cols (over i)
    k_head<<<1024, 256, 0, stream>>>(bufA, hW1, hb1, hW2, hb2, outp);
}

// Round 2
// 897.274 us; speedup vs baseline: 1.5880x; 1.5880x over previous
//
#include <hip/hip_runtime.h>
#include <hip/hip_bf16.h>
#include <math.h>

typedef unsigned short u16;
typedef u16 u16x8 __attribute__((ext_vector_type(8)));
typedef u16 u16x4 __attribute__((ext_vector_type(4)));
typedef __bf16 bf16x8 __attribute__((ext_vector_type(8)));
typedef float f32x4 __attribute__((ext_vector_type(4)));

__device__ __forceinline__ u16 f2bf(float f) {
    unsigned u = __builtin_bit_cast(unsigned, f);
    u += 0x7FFFu + ((u >> 16) & 1u);
    return (u16)(u >> 16);
}

#define MFMA16(A, B, C) __builtin_amdgcn_mfma_f32_16x16x32_bf16( \
    __builtin_bit_cast(bf16x8, A), __builtin_bit_cast(bf16x8, B), C, 0, 0, 0)

// ---------------- kernel 0: weight transpose + bf16 cast --------------------
__global__ __launch_bounds__(256) void k_prep(
    const float* __restrict__ fW2, const float* __restrict__ rW1,
    const float* __restrict__ rW2,
    u16* __restrict__ W2T, u16* __restrict__ rW1T, u16* __restrict__ rW2T)
{
    const int idx = blockIdx.x * 256 + threadIdx.x;
    if (idx < 256 * 128) {               // W2T[c][k] = fW2[k][c]
        const int c = idx >> 7, k = idx & 127;
        W2T[idx] = f2bf(fW2[k * 256 + c]);
    }
    const int i2 = idx - 256 * 128;
    if (i2 >= 0 && i2 < 64 * 128) {      // rW1T[d][k] = rW1[k][d]
        const int d = i2 >> 7, k = i2 & 127;
        rW1T[i2] = f2bf(rW1[k * 64 + d]);
    }
    const int i3 = idx - 256 * 128 - 64 * 128;
    if (i3 >= 0 && i3 < 32 * 64) {       // rW2T[e][d] = rW2[d][e]
        const int e = i3 >> 6, d = i3 & 63;
        rW2T[i3] = f2bf(rW2[d * 32 + e]);
    }
}

// ---------------- kernel 1: pi/pj = single @ film_W1 halves ----------------
__global__ __launch_bounds__(256) void k_pipj(const float* __restrict__ single,
                                              const float* __restrict__ fW1,
                                              float* __restrict__ pi,
                                              float* __restrict__ pj) {
    const int i = blockIdx.x;
    const int t = threadIdx.x;
    const int sel = t >> 7;
    const int c = t & 127;
    const float* srow = single + i * 256;
    const float* w = fW1 + sel * 256 * 128 + c;
    float acc = 0.f;
    for (int k = 0; k < 256; ++k) acc += srow[k] * w[k * 128];
    float* dst = sel ? pj : pi;
    dst[i * 128 + c] = acc;
}

// ------- kernel 2: fused FiLM -> gamma/beta -> reduction MLP (bf16 MFMA) ----
// Block: one i, 32 j's; 4 waves. All GEMMs computed transposed:
//   D[chan][j] = Wt[chan][k] @ act^T[k][j]
// A-frag: row=lane&15, k=(lane>>4)*8+e (contiguous) -> Wt rows from global.
// B-frag: col=lane&15, k=(lane>>4)*8+e -> act rows from swizzled LDS.
// C/D:    col(j)=lane&15, row(chan)=(lane>>4)*4+r.
__global__ __launch_bounds__(256) void k_film_red_mfma(
    const float* __restrict__ pair,  // [512][512][128]
    const float* __restrict__ pi,    // [512][128]
    const float* __restrict__ pj,    // [512][128]
    const float* __restrict__ fb1,   // [128]
    const u16*   __restrict__ W2T,   // [256][128] bf16 (pre-transposed)
    const float* __restrict__ fb2,   // [256]
    const u16*   __restrict__ rW1T,  // [64][128] bf16
    const float* __restrict__ rb1,   // [64]
    const u16*   __restrict__ rW2T,  // [32][64] bf16
    const float* __restrict__ rb2,   // [32]
    float* __restrict__ out)         // [512][512][32]
{
    __shared__ __align__(16) char hs [32 * 256];  // h  [j][k=128] bf16, swizzled
    __shared__ __align__(16) char p2s[32 * 256];  // p2 [j][k=128] bf16, swizzled
    __shared__ __align__(16) char t1s[32 * 128];  // t1 [j][d=64]  bf16, swizzled

    const int t = threadIdx.x;
    const int lane = t & 63, w = t >> 6;
    const int g = lane >> 4, ln = lane & 15;
    const int i = blockIdx.x >> 4;
    const int j0 = (blockIdx.x & 15) * 32;

    // ---- P0: h tile = relu(pi[i] + pj[j] + b1), bf16 into swizzled LDS ----
    {
        const int jj = t >> 3;            // 0..31
        const int k0 = (t & 7) * 16;      // 0..112
        const float* pir = pi + i * 128 + k0;
        const float* pjr = pj + (j0 + jj) * 128 + k0;
        const float* fbr = fb1 + k0;
        u16x8 pk0, pk1;
#pragma unroll
        for (int e = 0; e < 8; ++e) {
            float v0 = pir[e] + pjr[e] + fbr[e];
            float v1 = pir[8 + e] + pjr[8 + e] + fbr[8 + e];
            pk0[e] = f2bf(v0 > 0.f ? v0 : 0.f);
            pk1[e] = f2bf(v1 > 0.f ? v1 : 0.f);
        }
        const int sw = (jj & 7) << 4;
        *(u16x8*)(hs + jj * 256 + ((2 * k0) ^ sw)) = pk0;
        *(u16x8*)(hs + jj * 256 + ((2 * (k0 + 8)) ^ sw)) = pk1;
    }

    // ---- prefetch pair values this lane will modulate (hide HBM latency) ---
    f32x4 pr[2][2];
#pragma unroll
    for (int a2 = 0; a2 < 2; ++a2)
#pragma unroll
        for (int nt = 0; nt < 2; ++nt) {
            const int j = nt * 16 + ln;
            const int c0 = (w + 4 * a2) * 16 + g * 4;
            pr[a2][nt] = *(const f32x4*)(pair + ((long)(i * 512 + j0 + j)) * 128 + c0);
        }

    __syncthreads();

    // ---- GEMM1: x[c][j] = W2T[c][:] . h[j][:]   (M=256 via mt=w+4a) -------
    u16x8 bf1[2][4];
#pragma unroll
    for (int nt = 0; nt < 2; ++nt)
#pragma unroll
        for (int ks = 0; ks < 4; ++ks) {
            const int j = nt * 16 + ln;
            const int k = ks * 32 + g * 8;
            bf1[nt][ks] = *(const u16x8*)(hs + j * 256 + ((2 * k) ^ ((j & 7) << 4)));
        }
    u16x8 af1[4][4];
#pragma unroll
    for (int a = 0; a < 4; ++a)
#pragma unroll
        for (int ks = 0; ks < 4; ++ks) {
            const int row = (w + 4 * a) * 16 + ln;
            af1[a][ks] = *(const u16x8*)(W2T + row * 128 + ks * 32 + g * 8);
        }
    f32x4 acc[4][2] = {};
#pragma unroll
    for (int ks = 0; ks < 4; ++ks)
#pragma unroll
        for (int a = 0; a < 4; ++a)
#pragma unroll
            for (int nt = 0; nt < 2; ++nt)
                acc[a][nt] = MFMA16(af1[a][ks], bf1[nt][ks], acc[a][nt]);

    // ---- modulation: gamma/beta (c and c+128 live in same lane: a vs a+2) --
#pragma unroll
    for (int a2 = 0; a2 < 2; ++a2) {
        const int c0 = (w + 4 * a2) * 16 + g * 4;
        const f32x4 blo = *(const f32x4*)(fb2 + c0);
        const f32x4 bhi = *(const f32x4*)(fb2 + 128 + c0);
#pragma unroll
        for (int nt = 0; nt < 2; ++nt) {
            u16x4 pb;
#pragma unroll
            for (int r = 0; r < 4; ++r) {
                const float xlo = acc[a2][nt][r] + blo[r];
                const float xhi = acc[a2 + 2][nt][r] + bhi[r];
                const float gam = 1.f + 0.2f * tanhf(xlo);
                const float bet = 0.2f * tanhf(xhi);
                pb[r] = f2bf(gam * pr[a2][nt][r] + bet);
            }
            const int j = nt * 16 + ln;
            *(u16x4*)(p2s + j * 256 + ((2 * c0) ^ ((j & 7) << 4))) = pb;
        }
    }

    __syncthreads();

    // ---- GEMM2: red1[d][j] = rW1T[d][:] . p2[j][:]  (d-tile = wave) --------
    u16x8 bf2[2][4];
#pragma unroll
    for (int nt = 0; nt < 2; ++nt)
#pragma unroll
        for (int ks = 0; ks < 4; ++ks) {
            const int j = nt * 16 + ln;
            const int k = ks * 32 + g * 8;
            bf2[nt][ks] = *(const u16x8*)(p2s + j * 256 + ((2 * k) ^ ((j & 7) << 4)));
        }
    u16x8 af2[4];
#pragma unroll
    for (int ks = 0; ks < 4; ++ks)
        af2[ks] = *(const u16x8*)(rW1T + (w * 16 + ln) * 128 + ks * 32 + g * 8);
    f32x4 acc2[2] = {};
#pragma unroll
    for (int ks = 0; ks < 4; ++ks)
#pragma unroll
        for (int nt = 0; nt < 2; ++nt)
            acc2[nt] = MFMA16(af2[ks], bf2[nt][ks], acc2[nt]);

    // gelu (exact, erf) -> t1 LDS
    {
        const int d0 = w * 16 + g * 4;
        const f32x4 rb = *(const f32x4*)(rb1 + d0);
#pragma unroll
        for (int nt = 0; nt < 2; ++nt) {
            u16x4 tb;
#pragma unroll
            for (int r = 0; r < 4; ++r) {
                const float x = acc2[nt][r] + rb[r];
                tb[r] = f2bf(0.5f * x * (1.f + erff(x * 0.70710678118654752f)));
            }
            const int j = nt * 16 + ln;
            *(u16x4*)(t1s + j * 128 + ((2 * d0) ^ ((j & 7) << 4))) = tb;
        }
    }

    __syncthreads();

    // ---- GEMM3: out[e][j] = rW2T[e][:] . t1[j][:]  (wave -> (mt3,nt3)) -----
    {
        const int mt3 = w >> 1, nt3 = w & 1;
        f32x4 acc3 = {};
#pragma unroll
        for (int ks = 0; ks < 2; ++ks) {
            const u16x8 a3 = *(const u16x8*)(rW2T + (mt3 * 16 + ln) * 64 + ks * 32 + g * 8);
            const int j = nt3 * 16 + ln;
            const int k = ks * 32 + g * 8;
            const u16x8 b3 = *(const u16x8*)(t1s + j * 128 + ((2 * k) ^ ((j & 7) << 4)));
            acc3 = MFMA16(a3, b3, acc3);
        }
        const int e0 = mt3 * 16 + g * 4;
        const f32x4 rb = *(const f32x4*)(rb2 + e0);
        f32x4 o;
#pragma unroll
        for (int r = 0; r < 4; ++r) o[r] = acc3[r] + rb[r];
        const int j = nt3 * 16 + ln;
        *(f32x4*)(out + ((long)(i * 512 + j0 + j)) * 32 + e0) = o;
    }
}

// ---------------- kernel 3: windowed MHSA (64 tokens, 2 heads, C=32) --------
__global__ __launch_bounds__(128) void k_attn(
    const float* __restrict__ in,
    float* __restrict__ outbuf,
    const float* __restrict__ qW,  // [32][96]
    const float* __restrict__ qb,  // [96]
    const float* __restrict__ oW,  // [32][32]
    const float* __restrict__ ob,  // [32]
    const int col_pass)
{
    __shared__ float Xs[64][33];
    __shared__ float qWs[32][96];
    __shared__ float qkvs[64][100];
    __shared__ float os[64][33];
    __shared__ float oWs[32][32];
    __shared__ float qbs[96];
    __shared__ float obs[32];

    const int t = threadIdx.x;
    const int r = blockIdx.x >> 3;
    const int w = blockIdx.x & 7;
    long base; int stride;
    if (col_pass) { base = (long)(w * 64) * 512 * 32 + r * 32; stride = 512 * 32; }
    else          { base = ((long)r * 512 + w * 64) * 32;      stride = 32; }

    for (int u = t; u < 64 * 32; u += 128) {
        const int tok = u >> 5, c = u & 31;
        Xs[tok][c] = in[base + (long)tok * stride + c];
    }
    for (int u = t; u < 32 * 96; u += 128) qWs[u / 96][u % 96] = qW[u];
    for (int u = t; u < 32 * 32; u += 128) oWs[u >> 5][u & 31] = oW[u];
    if (t < 96) qbs[t] = qb[t];
    if (t < 32) obs[t] = ob[t];
    __syncthreads();

    for (int u = t; u < 64 * 96; u += 128) {
        const int tok = u / 96, col = u % 96;
        float s = qbs[col];
#pragma unroll
        for (int c = 0; c < 32; ++c) s += Xs[tok][c] * qWs[c][col];
        qkvs[tok][col] = s;
    }
    __syncthreads();

    {
        const int h = t >> 6, q = t & 63;
        float qv[16];
#pragma unroll
        for (int d = 0; d < 16; ++d) qv[d] = qkvs[q][h * 16 + d];
        float s[64];
        float mx = -1e30f;
        for (int kk = 0; kk < 64; ++kk) {
            float a = 0.f;
#pragma unroll
            for (int d = 0; d < 16; ++d) a += qv[d] * qkvs[kk][32 + h * 16 + d];
            a *= 0.25f;
            s[kk] = a;
            mx = fmaxf(mx, a);
        }
        float sum = 0.f;
        for (int kk = 0; kk < 64; ++kk) { s[kk] = expf(s[kk] - mx); sum += s[kk]; }
        const float inv = 1.f / sum;
        float o[16];
#pragma unroll
        for (int d = 0; d < 16; ++d) o[d] = 0.f;
        for (int kk = 0; kk < 64; ++kk) {
            const float a = s[kk];
#pragma unroll
            for (int d = 0; d < 16; ++d) o[d] += a * qkvs[kk][64 + h * 16 + d];
        }
#pragma unroll
        for (int d = 0; d < 16; ++d) os[q][h * 16 + d] = o[d] * inv;
    }
    __syncthreads();

    for (int u = t; u < 64 * 32; u += 128) {
        const int tok = u >> 5, c = u & 31;
        float s = obs[c];
#pragma unroll
        for (int d = 0; d < 32; ++d) s += os[tok][d] * oWs[d][c];
        outbuf[base + (long)tok * stride + c] = s;
    }
}

// ---------------- kernel 4: head MLP + sigmoid ------------------------------
__global__ __launch_bounds__(256) void k_head(
    const float* __restrict__ p3,
    const float* __restrict__ hW1,
    const float* __restrict__ hb1,
    const float* __restrict__ hW2,
    const float* __restrict__ hb2,
    float* __restrict__ outp)
{
    __shared__ float w1s[32][64];
    __shared__ float w2s[64];
    __shared__ float b1s[64];
    const int t = threadIdx.x;
    for (int u = t; u < 2048; u += 256) w1s[u >> 6][u & 63] = hW1[u];
    if (t < 64) { w2s[t] = hW2[t]; b1s[t] = hb1[t]; }
    __syncthreads();
    const float hb2v = hb2[0];

    const long idx = (long)blockIdx.x * 256 + t;
    const float4* xp = (const float4*)(p3 + idx * 32);
    float x[32];
#pragma unroll
    for (int q4 = 0; q4 < 8; ++q4) {
        const float4 v = xp[q4];
        x[q4 * 4 + 0] = v.x; x[q4 * 4 + 1] = v.y;
        x[q4 * 4 + 2] = v.z; x[q4 * 4 + 3] = v.w;
    }
    float logit = hb2v;
    for (int d = 0; d < 64; ++d) {
        float s = b1s[d];
#pragma unroll
        for (int c = 0; c < 32; ++c) s += x[c] * w1s[c][d];
        s = s > 0.f ? s : 0.f;
        logit += s * w2s[d];
    }
    outp[idx] = 1.f / (1.f + expf(-logit));
}

// ---------------------------------------------------------------------------
extern "C" void kernel_launch(void* const* d_in, const int* in_sizes, int n_in,
                              void* d_out, int out_size, void* d_ws, size_t ws_size,
                              hipStream_t stream) {
    (void)in_sizes; (void)n_in; (void)out_size; (void)ws_size;
    const float* single = (const float*)d_in[0];
    const float* pair   = (const float*)d_in[1];
    const float* fW1 = (const float*)d_in[2];
    const float* fb1 = (const float*)d_in[3];
    const float* fW2 = (const float*)d_in[4];
    const float* fb2 = (const float*)d_in[5];
    const float* rW1 = (const float*)d_in[6];
    const float* rb1 = (const float*)d_in[7];
    const float* rW2 = (const float*)d_in[8];
    const float* rb2 = (const float*)d_in[9];
    const float* qW  = (const float*)d_in[10];
    const float* qb  = (const float*)d_in[11];
    const float* oW  = (const float*)d_in[12];
    const float* ob  = (const float*)d_in[13];
    const float* hW1 = (const float*)d_in[14];
    const float* hb1 = (const float*)d_in[15];
    const float* hW2 = (const float*)d_in[16];
    const float* hb2 = (const float*)d_in[17];
    float* outp = (float*)d_out;

    char* ws = (char*)d_ws;
    float* pi   = (float*)ws;                          // 256 KB
    float* pj   = (float*)(ws + 256 * 1024);           // 256 KB
    u16*   W2T  = (u16*)(ws + 512 * 1024);             // 64 KB
    u16*   rW1T = (u16*)(ws + 576 * 1024);             // 16 KB
    u16*   rW2T = (u16*)(ws + 592 * 1024);             // 4 KB
    float* bufA = (float*)(ws + 1024 * 1024);          // 32 MB
    float* bufB = (float*)(ws + 1024 * 1024 + 33554432);

    k_prep<<<168, 256, 0, stream>>>(fW2, rW1, rW2, W2T, rW1T, rW2T);
    k_pipj<<<512, 256, 0, stream>>>(single, fW1, pi, pj);
    k_film_red_mfma<<<8192, 256, 0, stream>>>(pair, pi, pj, fb1, W2T, fb2,
                                              rW1T, rb1, rW2T, rb2, bufA);
    k_attn<<<4096, 128, 0, stream>>>(bufA, bufB, qW, qb, oW, ob, 0);
    k_attn<<<4096, 128, 0, stream>>>(bufB, bufA, qW, qb, oW, ob, 1);
    k_head<<<1024, 256, 0, stream>>>(bufA, hW1, hb1, hW2, hb2, outp);
}

// Round 3
// 428.643 us; speedup vs baseline: 3.3242x; 2.0933x over previous
//
#include <hip/hip_runtime.h>
#include <hip/hip_bf16.h>
#include <math.h>

typedef unsigned short u16;
typedef u16 u16x8 __attribute__((ext_vector_type(8)));
typedef u16 u16x4 __attribute__((ext_vector_type(4)));
typedef __bf16 bf16x8 __attribute__((ext_vector_type(8)));
typedef float f32x4 __attribute__((ext_vector_type(4)));

__device__ __forceinline__ u16 f2bf(float f) {
    unsigned u = __builtin_bit_cast(unsigned, f);
    u += 0x7FFFu + ((u >> 16) & 1u);
    return (u16)(u >> 16);
}

#define MFMA16(A, B, C) __builtin_amdgcn_mfma_f32_16x16x32_bf16( \
    __builtin_bit_cast(bf16x8, A), __builtin_bit_cast(bf16x8, B), C, 0, 0, 0)

// ---------------- kernel 0: weight transpose + bf16 cast --------------------
__global__ __launch_bounds__(256) void k_prep(
    const float* __restrict__ fW2, const float* __restrict__ rW1,
    const float* __restrict__ rW2, const float* __restrict__ qW,
    const float* __restrict__ oW,
    u16* __restrict__ W2T, u16* __restrict__ rW1T, u16* __restrict__ rW2T,
    u16* __restrict__ qWT, u16* __restrict__ oWT)
{
    const int idx = blockIdx.x * 256 + threadIdx.x;
    if (idx < 256 * 128) {               // W2T[c][k] = fW2[k][c]
        const int c = idx >> 7, k = idx & 127;
        W2T[idx] = f2bf(fW2[k * 256 + c]);
    }
    const int i2 = idx - 32768;
    if (i2 >= 0 && i2 < 64 * 128) {      // rW1T[d][k] = rW1[k][d]
        const int d = i2 >> 7, k = i2 & 127;
        rW1T[i2] = f2bf(rW1[k * 64 + d]);
    }
    const int i3 = idx - 40960;
    if (i3 >= 0 && i3 < 32 * 64) {       // rW2T[e][d] = rW2[d][e]
        const int e = i3 >> 6, d = i3 & 63;
        rW2T[i3] = f2bf(rW2[d * 32 + e]);
    }
    const int i4 = idx - 43008;
    if (i4 >= 0 && i4 < 96 * 32) {       // qWT[col][c] = qW[c][col]
        const int col = i4 >> 5, c = i4 & 31;
        qWT[i4] = f2bf(qW[c * 96 + col]);
    }
    const int i5 = idx - 46080;
    if (i5 >= 0 && i5 < 32 * 32) {       // oWT[oc][d] = oW[d][oc]
        const int oc = i5 >> 5, d = i5 & 31;
        oWT[i5] = f2bf(oW[d * 32 + oc]);
    }
}

// ---------------- kernel 1: pi/pj = single @ film_W1 halves ----------------
__global__ __launch_bounds__(256) void k_pipj(const float* __restrict__ single,
                                              const float* __restrict__ fW1,
                                              float* __restrict__ pi,
                                              float* __restrict__ pj) {
    const int i = blockIdx.x;
    const int t = threadIdx.x;
    const int sel = t >> 7;
    const int c = t & 127;
    const float* srow = single + i * 256;
    const float* w = fW1 + sel * 256 * 128 + c;
    float acc = 0.f;
    for (int k = 0; k < 256; ++k) acc += srow[k] * w[k * 128];
    float* dst = sel ? pj : pi;
    dst[i * 128 + c] = acc;
}

// ------- kernel 2: fused FiLM -> gamma/beta -> reduction MLP (bf16 MFMA) ----
__global__ __launch_bounds__(256) void k_film_red_mfma(
    const float* __restrict__ pair,  // [512][512][128]
    const float* __restrict__ pi,    // [512][128]
    const float* __restrict__ pj,    // [512][128]
    const float* __restrict__ fb1,   // [128]
    const u16*   __restrict__ W2T,   // [256][128] bf16 (pre-transposed)
    const float* __restrict__ fb2,   // [256]
    const u16*   __restrict__ rW1T,  // [64][128] bf16
    const float* __restrict__ rb1,   // [64]
    const u16*   __restrict__ rW2T,  // [32][64] bf16
    const float* __restrict__ rb2,   // [32]
    float* __restrict__ out)         // [512][512][32]
{
    __shared__ __align__(16) char hs [32 * 256];  // h  [j][k=128] bf16, swizzled
    __shared__ __align__(16) char p2s[32 * 256];  // p2 [j][k=128] bf16, swizzled
    __shared__ __align__(16) char t1s[32 * 128];  // t1 [j][d=64]  bf16, swizzled

    const int t = threadIdx.x;
    const int lane = t & 63, w = t >> 6;
    const int g = lane >> 4, ln = lane & 15;
    const int i = blockIdx.x >> 4;
    const int j0 = (blockIdx.x & 15) * 32;

    // ---- P0: h tile = relu(pi[i] + pj[j] + b1), bf16 into swizzled LDS ----
    {
        const int jj = t >> 3;            // 0..31
        const int k0 = (t & 7) * 16;      // 0..112
        const float* pir = pi + i * 128 + k0;
        const float* pjr = pj + (j0 + jj) * 128 + k0;
        const float* fbr = fb1 + k0;
        u16x8 pk0, pk1;
#pragma unroll
        for (int e = 0; e < 8; ++e) {
            float v0 = pir[e] + pjr[e] + fbr[e];
            float v1 = pir[8 + e] + pjr[8 + e] + fbr[8 + e];
            pk0[e] = f2bf(v0 > 0.f ? v0 : 0.f);
            pk1[e] = f2bf(v1 > 0.f ? v1 : 0.f);
        }
        const int sw = (jj & 7) << 4;
        *(u16x8*)(hs + jj * 256 + ((2 * k0) ^ sw)) = pk0;
        *(u16x8*)(hs + jj * 256 + ((2 * (k0 + 8)) ^ sw)) = pk1;
    }

    f32x4 pr[2][2];
#pragma unroll
    for (int a2 = 0; a2 < 2; ++a2)
#pragma unroll
        for (int nt = 0; nt < 2; ++nt) {
            const int j = nt * 16 + ln;
            const int c0 = (w + 4 * a2) * 16 + g * 4;
            pr[a2][nt] = *(const f32x4*)(pair + ((long)(i * 512 + j0 + j)) * 128 + c0);
        }

    __syncthreads();

    // ---- GEMM1: x[c][j] = W2T[c][:] . h[j][:] -----------------------------
    u16x8 bf1[2][4];
#pragma unroll
    for (int nt = 0; nt < 2; ++nt)
#pragma unroll
        for (int ks = 0; ks < 4; ++ks) {
            const int j = nt * 16 + ln;
            const int k = ks * 32 + g * 8;
            bf1[nt][ks] = *(const u16x8*)(hs + j * 256 + ((2 * k) ^ ((j & 7) << 4)));
        }
    u16x8 af1[4][4];
#pragma unroll
    for (int a = 0; a < 4; ++a)
#pragma unroll
        for (int ks = 0; ks < 4; ++ks) {
            const int row = (w + 4 * a) * 16 + ln;
            af1[a][ks] = *(const u16x8*)(W2T + row * 128 + ks * 32 + g * 8);
        }
    f32x4 acc[4][2] = {};
#pragma unroll
    for (int ks = 0; ks < 4; ++ks)
#pragma unroll
        for (int a = 0; a < 4; ++a)
#pragma unroll
            for (int nt = 0; nt < 2; ++nt)
                acc[a][nt] = MFMA16(af1[a][ks], bf1[nt][ks], acc[a][nt]);

    // ---- modulation --------------------------------------------------------
#pragma unroll
    for (int a2 = 0; a2 < 2; ++a2) {
        const int c0 = (w + 4 * a2) * 16 + g * 4;
        const f32x4 blo = *(const f32x4*)(fb2 + c0);
        const f32x4 bhi = *(const f32x4*)(fb2 + 128 + c0);
#pragma unroll
        for (int nt = 0; nt < 2; ++nt) {
            u16x4 pb;
#pragma unroll
            for (int r = 0; r < 4; ++r) {
                const float xlo = acc[a2][nt][r] + blo[r];
                const float xhi = acc[a2 + 2][nt][r] + bhi[r];
                const float gam = 1.f + 0.2f * tanhf(xlo);
                const float bet = 0.2f * tanhf(xhi);
                pb[r] = f2bf(gam * pr[a2][nt][r] + bet);
            }
            const int j = nt * 16 + ln;
            *(u16x4*)(p2s + j * 256 + ((2 * c0) ^ ((j & 7) << 4))) = pb;
        }
    }

    __syncthreads();

    // ---- GEMM2 -------------------------------------------------------------
    u16x8 bf2[2][4];
#pragma unroll
    for (int nt = 0; nt < 2; ++nt)
#pragma unroll
        for (int ks = 0; ks < 4; ++ks) {
            const int j = nt * 16 + ln;
            const int k = ks * 32 + g * 8;
            bf2[nt][ks] = *(const u16x8*)(p2s + j * 256 + ((2 * k) ^ ((j & 7) << 4)));
        }
    u16x8 af2[4];
#pragma unroll
    for (int ks = 0; ks < 4; ++ks)
        af2[ks] = *(const u16x8*)(rW1T + (w * 16 + ln) * 128 + ks * 32 + g * 8);
    f32x4 acc2[2] = {};
#pragma unroll
    for (int ks = 0; ks < 4; ++ks)
#pragma unroll
        for (int nt = 0; nt < 2; ++nt)
            acc2[nt] = MFMA16(af2[ks], bf2[nt][ks], acc2[nt]);

    {
        const int d0 = w * 16 + g * 4;
        const f32x4 rb = *(const f32x4*)(rb1 + d0);
#pragma unroll
        for (int nt = 0; nt < 2; ++nt) {
            u16x4 tb;
#pragma unroll
            for (int r = 0; r < 4; ++r) {
                const float x = acc2[nt][r] + rb[r];
                tb[r] = f2bf(0.5f * x * (1.f + erff(x * 0.70710678118654752f)));
            }
            const int j = nt * 16 + ln;
            *(u16x4*)(t1s + j * 128 + ((2 * d0) ^ ((j & 7) << 4))) = tb;
        }
    }

    __syncthreads();

    // ---- GEMM3 -------------------------------------------------------------
    {
        const int mt3 = w >> 1, nt3 = w & 1;
        f32x4 acc3 = {};
#pragma unroll
        for (int ks = 0; ks < 2; ++ks) {
            const u16x8 a3 = *(const u16x8*)(rW2T + (mt3 * 16 + ln) * 64 + ks * 32 + g * 8);
            const int j = nt3 * 16 + ln;
            const int k = ks * 32 + g * 8;
            const u16x8 b3 = *(const u16x8*)(t1s + j * 128 + ((2 * k) ^ ((j & 7) << 4)));
            acc3 = MFMA16(a3, b3, acc3);
        }
        const int e0 = mt3 * 16 + g * 4;
        const f32x4 rb = *(const f32x4*)(rb2 + e0);
        f32x4 o;
#pragma unroll
        for (int r = 0; r < 4; ++r) o[r] = acc3[r] + rb[r];
        const int j = nt3 * 16 + ln;
        *(f32x4*)(out + ((long)(i * 512 + j0 + j)) * 32 + e0) = o;
    }
}

// ------- kernel 3: windowed MHSA, full-MFMA, 2 windows per block ------------
// wave w: proj/outproj -> (wnd=w>>1, part p=w&1); attn core -> (wnd, head=w&1)
__global__ __launch_bounds__(256) void k_attn_mfma(
    const float* __restrict__ in, float* __restrict__ outbuf,
    const u16* __restrict__ qWT,   // [96][32] bf16: qWT[col][c] = qW[c][col]
    const float* __restrict__ qb,  // [96]
    const u16* __restrict__ oWT,   // [32][32] bf16: oWT[oc][d] = oW[d][oc]
    const float* __restrict__ ob,  // [32]
    const int col_pass)
{
    __shared__ u16 qWTs[96][40];
    __shared__ u16 oWTs[32][40];
    __shared__ float qbs[96];
    __shared__ float obs[32];
    __shared__ u16 Xs[2][64][40];      // X (proj input), later os (attn output)
    __shared__ u16 qks[2][64][72];     // q,k: cols 0..63
    __shared__ u16 vPs[2][2][16][72];  // [wnd][head][d][kk] V^T, k-permuted

    const int t = threadIdx.x;
    const int lane = t & 63, w = t >> 6;
    const int g = lane >> 4, ln = lane & 15;

    // ---- stage weights/biases ----
    for (int ch = t; ch < 96 * 4; ch += 256) {
        const int row = ch >> 2, p4 = ch & 3;
        *(u16x8*)&qWTs[row][p4 * 8] = *(const u16x8*)(qWT + row * 32 + p4 * 8);
    }
    if (t < 128) {
        const int row = t >> 2, p4 = t & 3;
        *(u16x8*)&oWTs[row][p4 * 8] = *(const u16x8*)(oWT + row * 32 + p4 * 8);
    }
    if (t < 96) qbs[t] = qb[t];
    if (t >= 128 && t < 160) obs[t - 128] = ob[t - 128];

    // ---- window bases ----
    const int wid0 = blockIdx.x * 2;
    long base[2]; int stride;
    if (col_pass) {
        stride = 512 * 32;
#pragma unroll
        for (int wnd = 0; wnd < 2; ++wnd) {
            const int id = wid0 + wnd;
            base[wnd] = (long)((id & 7) * 64) * (512 * 32) + (long)(id >> 3) * 32;
        }
    } else {
        stride = 32;
#pragma unroll
        for (int wnd = 0; wnd < 2; ++wnd) {
            const int id = wid0 + wnd;
            base[wnd] = ((long)(id >> 3) * 512 + (id & 7) * 64) * 32;
        }
    }

    // ---- stage X (f32 -> bf16) ----
    {
        const int wnd = t >> 7, rr = t & 127;
        const int tok = rr >> 1, c0 = (rr & 1) * 16;
        const float* src = in + base[wnd] + (long)tok * stride + c0;
        u16x8 a, b;
#pragma unroll
        for (int e = 0; e < 8; ++e) { a[e] = f2bf(src[e]); b[e] = f2bf(src[8 + e]); }
        *(u16x8*)&Xs[wnd][tok][c0] = a;
        *(u16x8*)&Xs[wnd][tok][c0 + 8] = b;
    }
    __syncthreads();

    // ---- projection: qkv = X @ qW + qb  (per wave: wnd, part p) ----
    {
        const int wnd = w >> 1, p = w & 1;
        u16x8 bw[4], bx[4];
#pragma unroll
        for (int nt = 0; nt < 4; ++nt) {
            bw[nt] = *(const u16x8*)&qWTs[nt * 16 + ln][g * 8];
            bx[nt] = *(const u16x8*)&Xs[wnd][nt * 16 + ln][g * 8];
        }
#pragma unroll
        for (int s = 0; s < 2; ++s) {          // tok-tiles 2p+s
            const u16x8 ax = bx[2 * p + s];
            f32x4 qa[4] = {};
#pragma unroll
            for (int nt = 0; nt < 4; ++nt)
                qa[nt] = MFMA16(ax, bw[nt], qa[nt]);
#pragma unroll
            for (int nt = 0; nt < 4; ++nt) {
                const float qbv = qbs[nt * 16 + ln];
#pragma unroll
                for (int r = 0; r < 4; ++r)
                    qks[wnd][(2 * p + s) * 16 + g * 4 + r][nt * 16 + ln] = f2bf(qa[nt][r] + qbv);
            }
        }
        // v-proj transposed + k-permuted: vPs[d][kk(tok)] = v[tok][d]
        const u16x8 av = *(const u16x8*)&qWTs[64 + p * 16 + ln][g * 8];
#pragma unroll
        for (int nt = 0; nt < 4; ++nt) {
            f32x4 va = MFMA16(av, bx[nt], ((f32x4){0.f, 0.f, 0.f, 0.f}));
            const int tok = nt * 16 + ln;
            const int kk = (tok & 32) | ((tok & 12) << 1) | ((tok & 16) >> 2) | (tok & 3);
#pragma unroll
            for (int r = 0; r < 4; ++r)
                vPs[wnd][p][g * 4 + r][kk] = f2bf(va[r] + qbs[64 + p * 16 + g * 4 + r]);
        }
    }
    __syncthreads();

    // ---- attention core (per wave: wnd, head h) ----
    {
        const int wnd = w >> 1, h = w & 1;
        const u16x8 zero8 = {};
        u16x8 bq[4];
#pragma unroll
        for (int nt = 0; nt < 4; ++nt)
            bq[nt] = (g < 2) ? *(const u16x8*)&qks[wnd][nt * 16 + ln][h * 16 + g * 8] : zero8;
        f32x4 s_[4][4] = {};
#pragma unroll
        for (int mt = 0; mt < 4; ++mt) {
            const u16x8 ak = (g < 2) ? *(const u16x8*)&qks[wnd][mt * 16 + ln][32 + h * 16 + g * 8] : zero8;
#pragma unroll
            for (int nt = 0; nt < 4; ++nt)
                s_[mt][nt] = MFMA16(ak, bq[nt], s_[mt][nt]);  // S^T[k][q]
        }
        // softmax over k (lane holds q = nt*16+ln; k = mt*16+g*4+r)
        u16x8 paf[4][2];
#pragma unroll
        for (int nt = 0; nt < 4; ++nt) {
            float mx = -1e30f;
#pragma unroll
            for (int mt = 0; mt < 4; ++mt)
#pragma unroll
                for (int r = 0; r < 4; ++r) {
                    s_[mt][nt][r] *= 0.25f;
                    mx = fmaxf(mx, s_[mt][nt][r]);
                }
            mx = fmaxf(mx, __shfl_xor(mx, 16));
            mx = fmaxf(mx, __shfl_xor(mx, 32));
            float sum = 0.f;
#pragma unroll
            for (int mt = 0; mt < 4; ++mt)
#pragma unroll
                for (int r = 0; r < 4; ++r) {
                    const float e_ = __expf(s_[mt][nt][r] - mx);
                    s_[mt][nt][r] = e_;
                    sum += e_;
                }
            sum += __shfl_xor(sum, 16);
            sum += __shfl_xor(sum, 32);
            const float inv = 1.f / sum;
            // PV A-frag, in-lane: elem e <-> k_phys = 32*s2 + 16*(e>>2) + 4*g + (e&3)
#pragma unroll
            for (int s2 = 0; s2 < 2; ++s2) {
                u16x8 pk;
#pragma unroll
                for (int e = 0; e < 8; ++e)
                    pk[e] = f2bf(s_[2 * s2 + (e >> 2)][nt][e & 3] * inv);
                paf[nt][s2] = pk;
            }
        }
        // PV: O[q][d] (B = pre-permuted V^T)
        u16x8 bv[2];
#pragma unroll
        for (int s2 = 0; s2 < 2; ++s2)
            bv[s2] = *(const u16x8*)&vPs[wnd][h][ln][s2 * 32 + g * 8];
        f32x4 oacc[4] = {};
#pragma unroll
        for (int nt = 0; nt < 4; ++nt)
#pragma unroll
            for (int s2 = 0; s2 < 2; ++s2)
                oacc[nt] = MFMA16(paf[nt][s2], bv[s2], oacc[nt]);
        // write os (overlays Xs): os[q][h*16+d]
#pragma unroll
        for (int nt = 0; nt < 4; ++nt)
#pragma unroll
            for (int r = 0; r < 4; ++r)
                Xs[wnd][nt * 16 + g * 4 + r][h * 16 + ln] = f2bf(oacc[nt][r]);
    }
    __syncthreads();

    // ---- out projection + store ----
    {
        const int wnd = w >> 1, p = w & 1;
        u16x8 bo[2];
#pragma unroll
        for (int nt = 0; nt < 2; ++nt)
            bo[nt] = *(const u16x8*)&oWTs[nt * 16 + ln][g * 8];
#pragma unroll
        for (int s = 0; s < 2; ++s) {
            const u16x8 ao = *(const u16x8*)&Xs[wnd][(2 * p + s) * 16 + ln][g * 8];
            f32x4 oa[2] = {};
#pragma unroll
            for (int nt = 0; nt < 2; ++nt)
                oa[nt] = MFMA16(ao, bo[nt], oa[nt]);
#pragma unroll
            for (int nt = 0; nt < 2; ++nt) {
                const int oc = nt * 16 + ln;
                const float obv = obs[oc];
#pragma unroll
                for (int r = 0; r < 4; ++r) {
                    const int tok = (2 * p + s) * 16 + g * 4 + r;
                    outbuf[base[wnd] + (long)tok * stride + oc] = oa[nt][r] + obv;
                }
            }
        }
    }
}

// ---------------- kernel 4: head MLP + sigmoid ------------------------------
__global__ __launch_bounds__(256) void k_head(
    const float* __restrict__ p3,
    const float* __restrict__ hW1,
    const float* __restrict__ hb1,
    const float* __restrict__ hW2,
    const float* __restrict__ hb2,
    float* __restrict__ outp)
{
    __shared__ float w1s[32][64];
    __shared__ float w2s[64];
    __shared__ float b1s[64];
    const int t = threadIdx.x;
    for (int u = t; u < 2048; u += 256) w1s[u >> 6][u & 63] = hW1[u];
    if (t < 64) { w2s[t] = hW2[t]; b1s[t] = hb1[t]; }
    __syncthreads();
    const float hb2v = hb2[0];

    const long idx = (long)blockIdx.x * 256 + t;
    const float4* xp = (const float4*)(p3 + idx * 32);
    float x[32];
#pragma unroll
    for (int q4 = 0; q4 < 8; ++q4) {
        const float4 v = xp[q4];
        x[q4 * 4 + 0] = v.x; x[q4 * 4 + 1] = v.y;
        x[q4 * 4 + 2] = v.z; x[q4 * 4 + 3] = v.w;
    }
    float logit = hb2v;
    for (int d = 0; d < 64; ++d) {
        float s = b1s[d];
#pragma unroll
        for (int c = 0; c < 32; ++c) s += x[c] * w1s[c][d];
        s = s > 0.f ? s : 0.f;
        logit += s * w2s[d];
    }
    outp[idx] = 1.f / (1.f + expf(-logit));
}

// ---------------------------------------------------------------------------
extern "C" void kernel_launch(void* const* d_in, const int* in_sizes, int n_in,
                              void* d_out, int out_size, void* d_ws, size_t ws_size,
                              hipStream_t stream) {
    (void)in_sizes; (void)n_in; (void)out_size; (void)ws_size;
    const float* single = (const float*)d_in[0];
    const float* pair   = (const float*)d_in[1];
    const float* fW1 = (const float*)d_in[2];
    const float* fb1 = (const float*)d_in[3];
    const float* fW2 = (const float*)d_in[4];
    const float* fb2 = (const float*)d_in[5];
    const float* rW1 = (const float*)d_in[6];
    const float* rb1 = (const float*)d_in[7];
    const float* rW2 = (const float*)d_in[8];
    const float* rb2 = (const float*)d_in[9];
    const float* qW  = (const float*)d_in[10];
    const float* qb  = (const float*)d_in[11];
    const float* oW  = (const float*)d_in[12];
    const float* ob  = (const float*)d_in[13];
    const float* hW1 = (const float*)d_in[14];
    const float* hb1 = (const float*)d_in[15];
    const float* hW2 = (const float*)d_in[16];
    const float* hb2 = (const float*)d_in[17];
    float* outp = (float*)d_out;

    char* ws = (char*)d_ws;
    float* pi   = (float*)ws;                          // 256 KB
    float* pj   = (float*)(ws + 256 * 1024);           // 256 KB
    u16*   W2T  = (u16*)(ws + 512 * 1024);             // 64 KB
    u16*   rW1T = (u16*)(ws + 576 * 1024);             // 16 KB
    u16*   rW2T = (u16*)(ws + 592 * 1024);             // 4 KB
    u16*   qWTd = (u16*)(ws + 608 * 1024);             // 6 KB
    u16*   oWTd = (u16*)(ws + 616 * 1024);             // 2 KB
    float* bufA = (float*)(ws + 1024 * 1024);          // 32 MB
    float* bufB = (float*)(ws + 1024 * 1024 + 33554432);

    k_prep<<<184, 256, 0, stream>>>(fW2, rW1, rW2, qW, oW, W2T, rW1T, rW2T, qWTd, oWTd);
    k_pipj<<<512, 256, 0, stream>>>(single, fW1, pi, pj);
    k_film_red_mfma<<<8192, 256, 0, stream>>>(pair, pi, pj, fb1, W2T, fb2,
                                              rW1T, rb1, rW2T, rb2, bufA);
    k_attn_mfma<<<2048, 256, 0, stream>>>(bufA, bufB, qWTd, qb, oWTd, ob, 0);
    k_attn_mfma<<<2048, 256, 0, stream>>>(bufB, bufA, qWTd, qb, oWTd, ob, 1);
    k_head<<<1024, 256, 0, stream>>>(bufA, hW1, hb1, hW2, hb2, outp);
}

// Round 4
// 403.285 us; speedup vs baseline: 3.5333x; 1.0629x over previous
//
#include <hip/hip_runtime.h>
#include <hip/hip_bf16.h>
#include <math.h>

typedef unsigned short u16;
typedef u16 u16x8 __attribute__((ext_vector_type(8)));
typedef u16 u16x4 __attribute__((ext_vector_type(4)));
typedef __bf16 bf16x8 __attribute__((ext_vector_type(8)));
typedef float f32x4 __attribute__((ext_vector_type(4)));

__device__ __forceinline__ u16 f2bf(float f) {
    return __builtin_bit_cast(u16, (__bf16)f);   // RNE, compiler pairs to cvt_pk
}
__device__ __forceinline__ float ftanh(float x) {
    // tanh(x) = 1 - 2/(exp(2x)+1); exp->v_exp_f32, rcp->v_rcp_f32
    const float e = __expf(2.f * x);
    return 1.f - 2.f * __builtin_amdgcn_rcpf(e + 1.f);
}
__device__ __forceinline__ float fgelu(float x) {
    // tanh-form gelu, |err| ~3e-4 abs; downstream gain ~0.16 -> safe vs 1e-2
    const float u = 0.7978845608028654f * x * (1.f + 0.044715f * x * x);
    return 0.5f * x * (1.f + ftanh(u));
}

#define MFMA16(A, B, C) __builtin_amdgcn_mfma_f32_16x16x32_bf16( \
    __builtin_bit_cast(bf16x8, A), __builtin_bit_cast(bf16x8, B), C, 0, 0, 0)

// raw barrier: drains LDS only; global loads stay in flight across it
#define BARRIER() do { \
    asm volatile("s_waitcnt lgkmcnt(0)" ::: "memory"); \
    __builtin_amdgcn_s_barrier(); \
    __builtin_amdgcn_sched_barrier(0); \
} while (0)

// ---------------- kernel 0: weight transpose + bf16 cast --------------------
__global__ __launch_bounds__(256) void k_prep(
    const float* __restrict__ fW2, const float* __restrict__ rW1,
    const float* __restrict__ rW2, const float* __restrict__ qW,
    const float* __restrict__ oW,
    u16* __restrict__ W2T, u16* __restrict__ rW1T, u16* __restrict__ rW2T,
    u16* __restrict__ qWT, u16* __restrict__ oWT)
{
    const int idx = blockIdx.x * 256 + threadIdx.x;
    if (idx < 256 * 128) {               // W2T[c][k] = fW2[k][c]
        const int c = idx >> 7, k = idx & 127;
        W2T[idx] = f2bf(fW2[k * 256 + c]);
    }
    const int i2 = idx - 32768;
    if (i2 >= 0 && i2 < 64 * 128) {      // rW1T[d][k] = rW1[k][d]
        const int d = i2 >> 7, k = i2 & 127;
        rW1T[i2] = f2bf(rW1[k * 64 + d]);
    }
    const int i3 = idx - 40960;
    if (i3 >= 0 && i3 < 32 * 64) {       // rW2T[e][d] = rW2[d][e]
        const int e = i3 >> 6, d = i3 & 63;
        rW2T[i3] = f2bf(rW2[d * 32 + e]);
    }
    const int i4 = idx - 43008;
    if (i4 >= 0 && i4 < 96 * 32) {       // qWT[col][c] = qW[c][col]
        const int col = i4 >> 5, c = i4 & 31;
        qWT[i4] = f2bf(qW[c * 96 + col]);
    }
    const int i5 = idx - 46080;
    if (i5 >= 0 && i5 < 32 * 32) {       // oWT[oc][d] = oW[d][oc]
        const int oc = i5 >> 5, d = i5 & 31;
        oWT[i5] = f2bf(oW[d * 32 + oc]);
    }
}

// -------- kernel 1: pi = single@fW1[:256] + fb1 ; pj = single@fW1[256:] -----
__global__ __launch_bounds__(256) void k_pipj(const float* __restrict__ single,
                                              const float* __restrict__ fW1,
                                              const float* __restrict__ fb1,
                                              float* __restrict__ pi,
                                              float* __restrict__ pj) {
    const int i = blockIdx.x;
    const int t = threadIdx.x;
    const int sel = t >> 7;
    const int c = t & 127;
    const float* srow = single + i * 256;
    const float* w = fW1 + sel * 256 * 128 + c;
    float acc = 0.f;
    for (int k = 0; k < 256; ++k) acc += srow[k] * w[k * 128];
    if (sel == 0) acc += fb1[c];   // fold film_b1 into pi
    float* dst = sel ? pj : pi;
    dst[i * 128 + c] = acc;
}

// ------- kernel 2: fused FiLM -> gamma/beta -> reduction MLP (bf16 MFMA) ----
__global__ __launch_bounds__(256) void k_film_red_mfma(
    const float* __restrict__ pair,  // [512][512][128]
    const float* __restrict__ pi,    // [512][128] (includes fb1)
    const float* __restrict__ pj,    // [512][128]
    const u16*   __restrict__ W2T,   // [256][128] bf16
    const float* __restrict__ fb2,   // [256]
    const u16*   __restrict__ rW1T,  // [64][128] bf16
    const float* __restrict__ rb1,   // [64]
    const u16*   __restrict__ rW2T,  // [32][64] bf16
    const float* __restrict__ rb2,   // [32]
    float* __restrict__ out)         // [512][512][32]
{
    __shared__ __align__(16) char hs [32 * 256];  // h  [j][k=128] bf16, swizzled
    __shared__ __align__(16) char p2s[32 * 256];  // p2 [j][k=128] bf16, swizzled
    __shared__ __align__(16) char t1s[32 * 128];  // t1 [j][d=64]  bf16, swizzled

    const int t = threadIdx.x;
    const int lane = t & 63, w = t >> 6;
    const int g = lane >> 4, ln = lane & 15;
    const int i = blockIdx.x >> 4;
    const int j0 = (blockIdx.x & 15) * 32;

    // ---- P0 loads issued first (earliest vmcnt slots) ----
    const int jj = t >> 3;            // 0..31
    const int k0 = (t & 7) * 16;      // 0..112
    const float* pir = pi + i * 128 + k0;
    const float* pjr = pj + (j0 + jj) * 128 + k0;
    f32x4 pv[4], qv[4];
#pragma unroll
    for (int q4 = 0; q4 < 4; ++q4) {
        pv[q4] = *(const f32x4*)(pir + 4 * q4);
        qv[q4] = *(const f32x4*)(pjr + 4 * q4);
    }

    // ---- hoisted GEMM1 A-operand weight loads (ride across barriers) ----
    u16x8 af1[4][4];
#pragma unroll
    for (int a = 0; a < 4; ++a)
#pragma unroll
        for (int ks = 0; ks < 4; ++ks)
            af1[a][ks] = *(const u16x8*)(W2T + ((w + 4 * a) * 16 + ln) * 128 + ks * 32 + g * 8);

    // ---- pair prefetch (consumed in modulation phase) ----
    f32x4 pr[2][2];
#pragma unroll
    for (int a2 = 0; a2 < 2; ++a2)
#pragma unroll
        for (int nt = 0; nt < 2; ++nt) {
            const int j = nt * 16 + ln;
            const int c0 = (w + 4 * a2) * 16 + g * 4;
            pr[a2][nt] = *(const f32x4*)(pair + ((long)(i * 512 + j0 + j)) * 128 + c0);
        }

    // ---- P0 compute: h = relu(pi'+pj) -> bf16 swizzled LDS ----
    {
        u16x8 pk0, pk1;
#pragma unroll
        for (int e = 0; e < 8; ++e) {
            const float v0 = pv[e >> 2][e & 3] + qv[e >> 2][e & 3];
            const float v1 = pv[2 + (e >> 2)][e & 3] + qv[2 + (e >> 2)][e & 3];
            pk0[e] = f2bf(fmaxf(v0, 0.f));
            pk1[e] = f2bf(fmaxf(v1, 0.f));
        }
        const int sw = (jj & 7) << 4;
        *(u16x8*)(hs + jj * 256 + ((2 * k0) ^ sw)) = pk0;
        *(u16x8*)(hs + jj * 256 + ((2 * (k0 + 8)) ^ sw)) = pk1;
    }
    BARRIER();

    // ---- GEMM1: x[c][j] = W2T[c][:] . h[j][:] ----
    f32x4 acc[4][2] = {};
#pragma unroll
    for (int ks = 0; ks < 4; ++ks) {
        u16x8 b0, b1;
        {
            const int jA = ln, jB = 16 + ln;
            const int k = ks * 32 + g * 8;
            b0 = *(const u16x8*)(hs + jA * 256 + ((2 * k) ^ ((jA & 7) << 4)));
            b1 = *(const u16x8*)(hs + jB * 256 + ((2 * k) ^ ((jB & 7) << 4)));
        }
#pragma unroll
        for (int a = 0; a < 4; ++a) {
            acc[a][0] = MFMA16(af1[a][ks], b0, acc[a][0]);
            acc[a][1] = MFMA16(af1[a][ks], b1, acc[a][1]);
        }
    }

    // ---- issue GEMM2 A-operands now (overlap with modulation VALU) ----
    u16x8 af2[4];
#pragma unroll
    for (int ks = 0; ks < 4; ++ks)
        af2[ks] = *(const u16x8*)(rW1T + (w * 16 + ln) * 128 + ks * 32 + g * 8);

    // ---- modulation: gamma/beta (fast tanh) -> p2s ----
#pragma unroll
    for (int a2 = 0; a2 < 2; ++a2) {
        const int c0 = (w + 4 * a2) * 16 + g * 4;
        const f32x4 blo = *(const f32x4*)(fb2 + c0);
        const f32x4 bhi = *(const f32x4*)(fb2 + 128 + c0);
#pragma unroll
        for (int nt = 0; nt < 2; ++nt) {
            u16x4 pb;
#pragma unroll
            for (int r = 0; r < 4; ++r) {
                const float xlo = acc[a2][nt][r] + blo[r];
                const float xhi = acc[a2 + 2][nt][r] + bhi[r];
                const float gam = 1.f + 0.2f * ftanh(xlo);
                const float bet = 0.2f * ftanh(xhi);
                pb[r] = f2bf(gam * pr[a2][nt][r] + bet);
            }
            const int j = nt * 16 + ln;
            *(u16x4*)(p2s + j * 256 + ((2 * c0) ^ ((j & 7) << 4))) = pb;
        }
    }
    BARRIER();

    // ---- GEMM3 A-operands issued here (overlap GEMM2) ----
    const int mt3 = w >> 1, nt3 = w & 1;
    u16x8 a3[2];
#pragma unroll
    for (int ks = 0; ks < 2; ++ks)
        a3[ks] = *(const u16x8*)(rW2T + (mt3 * 16 + ln) * 64 + ks * 32 + g * 8);

    // ---- GEMM2: red1[d][j] = rW1T[d][:] . p2[j][:] ----
    f32x4 acc2[2] = {};
#pragma unroll
    for (int ks = 0; ks < 4; ++ks) {
        const int k = ks * 32 + g * 8;
        const int jA = ln, jB = 16 + ln;
        const u16x8 b0 = *(const u16x8*)(p2s + jA * 256 + ((2 * k) ^ ((jA & 7) << 4)));
        const u16x8 b1 = *(const u16x8*)(p2s + jB * 256 + ((2 * k) ^ ((jB & 7) << 4)));
        acc2[0] = MFMA16(af2[ks], b0, acc2[0]);
        acc2[1] = MFMA16(af2[ks], b1, acc2[1]);
    }

    // gelu (fast tanh form) -> t1s
    {
        const int d0 = w * 16 + g * 4;
        const f32x4 rb = *(const f32x4*)(rb1 + d0);
#pragma unroll
        for (int nt = 0; nt < 2; ++nt) {
            u16x4 tb;
#pragma unroll
            for (int r = 0; r < 4; ++r)
                tb[r] = f2bf(fgelu(acc2[nt][r] + rb[r]));
            const int j = nt * 16 + ln;
            *(u16x4*)(t1s + j * 128 + ((2 * d0) ^ ((j & 7) << 4))) = tb;
        }
    }
    BARRIER();

    // ---- GEMM3: out[e][j] = rW2T[e][:] . t1[j][:] ----
    {
        f32x4 acc3 = {};
#pragma unroll
        for (int ks = 0; ks < 2; ++ks) {
            const int j = nt3 * 16 + ln;
            const int k = ks * 32 + g * 8;
            const u16x8 b3 = *(const u16x8*)(t1s + j * 128 + ((2 * k) ^ ((j & 7) << 4)));
            acc3 = MFMA16(a3[ks], b3, acc3);
        }
        const int e0 = mt3 * 16 + g * 4;
        const f32x4 rb = *(const f32x4*)(rb2 + e0);
        f32x4 o;
#pragma unroll
        for (int r = 0; r < 4; ++r) o[r] = acc3[r] + rb[r];
        const int j = nt3 * 16 + ln;
        *(f32x4*)(out + ((long)(i * 512 + j0 + j)) * 32 + e0) = o;
    }
}

// ------- kernel 3: windowed MHSA, full-MFMA, 1 window / 128-thread block ----
// weights read as MFMA fragments directly from global (L1-hot, ~8KB total)
__global__ __launch_bounds__(128) void k_attn_mfma(
    const float* __restrict__ in, float* __restrict__ outbuf,
    const u16* __restrict__ qWT,   // [96][32] bf16: qWT[col][c] = qW[c][col]
    const float* __restrict__ qb,  // [96]
    const u16* __restrict__ oWT,   // [32][32] bf16: oWT[oc][d] = oW[d][oc]
    const float* __restrict__ ob,  // [32]
    const int col_pass)
{
    __shared__ u16 Xs[64][40];     // X (proj input), later os (attn output)
    __shared__ u16 qks[64][72];    // q,k
    __shared__ u16 vPs[2][16][72]; // [head][d][kk] V^T, k-permuted

    const int t = threadIdx.x;
    const int lane = t & 63, w = t >> 6;   // w in {0,1}
    const int g = lane >> 4, ln = lane & 15;
    const int p = w;

    const int id = blockIdx.x;
    long base; int stride;
    if (col_pass) { stride = 512 * 32; base = (long)((id & 7) * 64) * (512 * 32) + (long)(id >> 3) * 32; }
    else          { stride = 32;       base = ((long)(id >> 3) * 512 + (id & 7) * 64) * 32; }

    // ---- weight fragments / biases direct from global (issue early) ----
    u16x8 bw[4];
#pragma unroll
    for (int nt = 0; nt < 4; ++nt)
        bw[nt] = *(const u16x8*)(qWT + (nt * 16 + ln) * 32 + g * 8);
    const u16x8 av = *(const u16x8*)(qWT + (64 + p * 16 + ln) * 32 + g * 8);
    float qbias[4];
#pragma unroll
    for (int nt = 0; nt < 4; ++nt) qbias[nt] = qb[nt * 16 + ln];
    const f32x4 vb = *(const f32x4*)(qb + 64 + p * 16 + g * 4);

    // ---- stage X (f32 -> bf16) ----
    {
        const int tok = t >> 1, c0 = (t & 1) * 16;
        const float* src = in + base + (long)tok * stride + c0;
        u16x8 a, b;
#pragma unroll
        for (int e = 0; e < 8; ++e) { a[e] = f2bf(src[e]); b[e] = f2bf(src[8 + e]); }
        *(u16x8*)&Xs[tok][c0] = a;
        *(u16x8*)&Xs[tok][c0 + 8] = b;
    }
    BARRIER();

    // ---- projection: qkv = X @ qW + qb  (wave = part p) ----
    {
        u16x8 bx[4];
#pragma unroll
        for (int nt = 0; nt < 4; ++nt)
            bx[nt] = *(const u16x8*)&Xs[nt * 16 + ln][g * 8];
#pragma unroll
        for (int s = 0; s < 2; ++s) {          // tok-tiles 2p+s
            const u16x8 ax = bx[2 * p + s];
            f32x4 qa[4] = {};
#pragma unroll
            for (int nt = 0; nt < 4; ++nt)
                qa[nt] = MFMA16(ax, bw[nt], qa[nt]);
#pragma unroll
            for (int nt = 0; nt < 4; ++nt)
#pragma unroll
                for (int r = 0; r < 4; ++r)
                    qks[(2 * p + s) * 16 + g * 4 + r][nt * 16 + ln] = f2bf(qa[nt][r] + qbias[nt]);
        }
        // v-proj transposed + k-permuted: vPs[p][d][kk(tok)] = v[tok][d]
#pragma unroll
        for (int nt = 0; nt < 4; ++nt) {
            f32x4 va = MFMA16(av, bx[nt], ((f32x4){0.f, 0.f, 0.f, 0.f}));
            const int tok = nt * 16 + ln;
            const int kk = (tok & 32) | ((tok & 12) << 1) | ((tok & 16) >> 2) | (tok & 3);
#pragma unroll
            for (int r = 0; r < 4; ++r)
                vPs[p][g * 4 + r][kk] = f2bf(va[r] + vb[r]);
        }
    }
    BARRIER();

    // ---- attention core (wave = head h) ----
    {
        const int h = w;
        const u16x8 zero8 = {};
        u16x8 bq[4];
#pragma unroll
        for (int nt = 0; nt < 4; ++nt)
            bq[nt] = (g < 2) ? *(const u16x8*)&qks[nt * 16 + ln][h * 16 + g * 8] : zero8;
        f32x4 s_[4][4] = {};
#pragma unroll
        for (int mt = 0; mt < 4; ++mt) {
            const u16x8 ak = (g < 2) ? *(const u16x8*)&qks[mt * 16 + ln][32 + h * 16 + g * 8] : zero8;
#pragma unroll
            for (int nt = 0; nt < 4; ++nt)
                s_[mt][nt] = MFMA16(ak, bq[nt], s_[mt][nt]);  // S^T[k][q]
        }
        u16x8 paf[4][2];
#pragma unroll
        for (int nt = 0; nt < 4; ++nt) {
            float mx = -1e30f;
#pragma unroll
            for (int mt = 0; mt < 4; ++mt)
#pragma unroll
                for (int r = 0; r < 4; ++r) {
                    s_[mt][nt][r] *= 0.25f;
                    mx = fmaxf(mx, s_[mt][nt][r]);
                }
            mx = fmaxf(mx, __shfl_xor(mx, 16));
            mx = fmaxf(mx, __shfl_xor(mx, 32));
            float sum = 0.f;
#pragma unroll
            for (int mt = 0; mt < 4; ++mt)
#pragma unroll
                for (int r = 0; r < 4; ++r) {
                    const float e_ = __expf(s_[mt][nt][r] - mx);
                    s_[mt][nt][r] = e_;
                    sum += e_;
                }
            sum += __shfl_xor(sum, 16);
            sum += __shfl_xor(sum, 32);
            const float inv = __builtin_amdgcn_rcpf(sum);
#pragma unroll
            for (int s2 = 0; s2 < 2; ++s2) {
                u16x8 pk;
#pragma unroll
                for (int e = 0; e < 8; ++e)
                    pk[e] = f2bf(s_[2 * s2 + (e >> 2)][nt][e & 3] * inv);
                paf[nt][s2] = pk;
            }
        }
        u16x8 bv[2];
#pragma unroll
        for (int s2 = 0; s2 < 2; ++s2)
            bv[s2] = *(const u16x8*)&vPs[h][ln][s2 * 32 + g * 8];
        f32x4 oacc[4] = {};
#pragma unroll
        for (int nt = 0; nt < 4; ++nt)
#pragma unroll
            for (int s2 = 0; s2 < 2; ++s2)
                oacc[nt] = MFMA16(paf[nt][s2], bv[s2], oacc[nt]);
#pragma unroll
        for (int nt = 0; nt < 4; ++nt)
#pragma unroll
            for (int r = 0; r < 4; ++r)
                Xs[nt * 16 + g * 4 + r][h * 16 + ln] = f2bf(oacc[nt][r]);
    }
    BARRIER();

    // ---- out projection + store ----
    {
        u16x8 bo[2];
#pragma unroll
        for (int nt = 0; nt < 2; ++nt)
            bo[nt] = *(const u16x8*)(oWT + (nt * 16 + ln) * 32 + g * 8);
        float ob2[2];
#pragma unroll
        for (int nt = 0; nt < 2; ++nt) ob2[nt] = ob[nt * 16 + ln];
#pragma unroll
        for (int s = 0; s < 2; ++s) {
            const u16x8 ao = *(const u16x8*)&Xs[(2 * p + s) * 16 + ln][g * 8];
            f32x4 oa[2] = {};
#pragma unroll
            for (int nt = 0; nt < 2; ++nt)
                oa[nt] = MFMA16(ao, bo[nt], oa[nt]);
#pragma unroll
            for (int nt = 0; nt < 2; ++nt) {
                const int oc = nt * 16 + ln;
#pragma unroll
                for (int r = 0; r < 4; ++r) {
                    const int tok = (2 * p + s) * 16 + g * 4 + r;
                    outbuf[base + (long)tok * stride + oc] = oa[nt][r] + ob2[nt];
                }
            }
        }
    }
}

// ---------------- kernel 4: head MLP + sigmoid ------------------------------
__global__ __launch_bounds__(256) void k_head(
    const float* __restrict__ p3,
    const float* __restrict__ hW1,
    const float* __restrict__ hb1,
    const float* __restrict__ hW2,
    const float* __restrict__ hb2,
    float* __restrict__ outp)
{
    __shared__ float w1s[32][64];
    __shared__ float w2s[64];
    __shared__ float b1s[64];
    const int t = threadIdx.x;
    for (int u = t; u < 2048; u += 256) w1s[u >> 6][u & 63] = hW1[u];
    if (t < 64) { w2s[t] = hW2[t]; b1s[t] = hb1[t]; }
    __syncthreads();
    const float hb2v = hb2[0];

    const long idx = (long)blockIdx.x * 256 + t;
    const float4* xp = (const float4*)(p3 + idx * 32);
    float x[32];
#pragma unroll
    for (int q4 = 0; q4 < 8; ++q4) {
        const float4 v = xp[q4];
        x[q4 * 4 + 0] = v.x; x[q4 * 4 + 1] = v.y;
        x[q4 * 4 + 2] = v.z; x[q4 * 4 + 3] = v.w;
    }
    float logit = hb2v;
    for (int d = 0; d < 64; ++d) {
        float s = b1s[d];
#pragma unroll
        for (int c = 0; c < 32; ++c) s += x[c] * w1s[c][d];
        s = s > 0.f ? s : 0.f;
        logit += s * w2s[d];
    }
    outp[idx] = __builtin_amdgcn_rcpf(1.f + __expf(-logit));
}

// ---------------------------------------------------------------------------
extern "C" void kernel_launch(void* const* d_in, const int* in_sizes, int n_in,
                              void* d_out, int out_size, void* d_ws, size_t ws_size,
                              hipStream_t stream) {
    (void)in_sizes; (void)n_in; (void)out_size; (void)ws_size;
    const float* single = (const float*)d_in[0];
    const float* pair   = (const float*)d_in[1];
    const float* fW1 = (const float*)d_in[2];
    const float* fb1 = (const float*)d_in[3];
    const float* fW2 = (const float*)d_in[4];
    const float* fb2 = (const float*)d_in[5];
    const float* rW1 = (const float*)d_in[6];
    const float* rb1 = (const float*)d_in[7];
    const float* rW2 = (const float*)d_in[8];
    const float* rb2 = (const float*)d_in[9];
    const float* qW  = (const float*)d_in[10];
    const float* qb  = (const float*)d_in[11];
    const float* oW  = (const float*)d_in[12];
    const float* ob  = (const float*)d_in[13];
    const float* hW1 = (const float*)d_in[14];
    const float* hb1 = (const float*)d_in[15];
    const float* hW2 = (const float*)d_in[16];
    const float* hb2 = (const float*)d_in[17];
    float* outp = (float*)d_out;

    char* ws = (char*)d_ws;
    float* pi   = (float*)ws;                          // 256 KB
    float* pj   = (float*)(ws + 256 * 1024);           // 256 KB
    u16*   W2T  = (u16*)(ws + 512 * 1024);             // 64 KB
    u16*   rW1T = (u16*)(ws + 576 * 1024);             // 16 KB
    u16*   rW2T = (u16*)(ws + 592 * 1024);             // 4 KB
    u16*   qWTd = (u16*)(ws + 608 * 1024);             // 6 KB
    u16*   oWTd = (u16*)(ws + 616 * 1024);             // 2 KB
    float* bufA = (float*)(ws + 1024 * 1024);          // 32 MB
    float* bufB = (float*)(ws + 1024 * 1024 + 33554432);

    k_prep<<<184, 256, 0, stream>>>(fW2, rW1, rW2, qW, oW, W2T, rW1T, rW2T, qWTd, oWTd);
    k_pipj<<<512, 256, 0, stream>>>(single, fW1, fb1, pi, pj);
    k_film_red_mfma<<<8192, 256, 0, stream>>>(pair, pi, pj, W2T, fb2,
                                              rW1T, rb1, rW2T, rb2, bufA);
    k_attn_mfma<<<4096, 128, 0, stream>>>(bufA, bufB, qWTd, qb, oWTd, ob, 0);
    k_attn_mfma<<<4096, 128, 0, stream>>>(bufB, bufA, qWTd, qb, oWTd, ob, 1);
    k_head<<<1024, 256, 0, stream>>>(bufA, hW1, hb1, hW2, hb2, outp);
}

// Round 5
// 342.835 us; speedup vs baseline: 4.1563x; 1.1763x over previous
//
#include <hip/hip_runtime.h>
#include <hip/hip_bf16.h>
#include <math.h>

typedef unsigned short u16;
typedef u16 u16x8 __attribute__((ext_vector_type(8)));
typedef u16 u16x4 __attribute__((ext_vector_type(4)));
typedef __bf16 bf16x8 __attribute__((ext_vector_type(8)));
typedef float f32x4 __attribute__((ext_vector_type(4)));

__device__ __forceinline__ u16 f2bf(float f) {
    return __builtin_bit_cast(u16, (__bf16)f);   // RNE, pairs into cvt_pk
}
__device__ __forceinline__ float ftanh(float x) {
    const float e = __expf(2.f * x);
    return 1.f - 2.f * __builtin_amdgcn_rcpf(e + 1.f);
}
__device__ __forceinline__ float fgelu(float x) {
    const float u = 0.7978845608028654f * x * (1.f + 0.044715f * x * x);
    return 0.5f * x * (1.f + ftanh(u));
}

#define MFMA16(A, B, C) __builtin_amdgcn_mfma_f32_16x16x32_bf16( \
    __builtin_bit_cast(bf16x8, A), __builtin_bit_cast(bf16x8, B), C, 0, 0, 0)

// raw barrier: drains LDS only; global loads stay in flight across it
#define BARRIER() do { \
    asm volatile("s_waitcnt lgkmcnt(0)" ::: "memory"); \
    __builtin_amdgcn_s_barrier(); \
    __builtin_amdgcn_sched_barrier(0); \
} while (0)

// ---------------- kernel 0: weight transpose + bf16 cast --------------------
__global__ __launch_bounds__(256) void k_prep(
    const float* __restrict__ fW2, const float* __restrict__ rW1,
    const float* __restrict__ rW2, const float* __restrict__ qW,
    const float* __restrict__ oW, const float* __restrict__ hW1,
    u16* __restrict__ W2T, u16* __restrict__ rW1T, u16* __restrict__ rW2T,
    u16* __restrict__ qWT, u16* __restrict__ oWT, u16* __restrict__ hW1T)
{
    const int idx = blockIdx.x * 256 + threadIdx.x;
    if (idx < 256 * 128) {               // W2T[c][k] = fW2[k][c]
        const int c = idx >> 7, k = idx & 127;
        W2T[idx] = f2bf(fW2[k * 256 + c]);
    }
    const int i2 = idx - 32768;
    if (i2 >= 0 && i2 < 64 * 128) {      // rW1T[d][k] = rW1[k][d]
        const int d = i2 >> 7, k = i2 & 127;
        rW1T[i2] = f2bf(rW1[k * 64 + d]);
    }
    const int i3 = idx - 40960;
    if (i3 >= 0 && i3 < 32 * 64) {       // rW2T[e][d] = rW2[d][e]
        const int e = i3 >> 6, d = i3 & 63;
        rW2T[i3] = f2bf(rW2[d * 32 + e]);
    }
    const int i4 = idx - 43008;
    if (i4 >= 0 && i4 < 96 * 32) {       // qWT[col][c] = qW[c][col]
        const int col = i4 >> 5, c = i4 & 31;
        qWT[i4] = f2bf(qW[c * 96 + col]);
    }
    const int i5 = idx - 46080;
    if (i5 >= 0 && i5 < 32 * 32) {       // oWT[oc][d] = oW[d][oc]
        const int oc = i5 >> 5, d = i5 & 31;
        oWT[i5] = f2bf(oW[d * 32 + oc]);
    }
    const int i6 = idx - 47104;
    if (i6 >= 0 && i6 < 64 * 32) {       // hW1T[d][c] = hW1[c][d]
        const int d = i6 >> 5, c = i6 & 31;
        hW1T[i6] = f2bf(hW1[c * 64 + d]);
    }
}

// -------- kernel 1: pi = single@fW1[:256] + fb1 ; pj = single@fW1[256:] -----
__global__ __launch_bounds__(256) void k_pipj(const float* __restrict__ single,
                                              const float* __restrict__ fW1,
                                              const float* __restrict__ fb1,
                                              float* __restrict__ pi,
                                              float* __restrict__ pj) {
    const int i = blockIdx.x;
    const int t = threadIdx.x;
    const int sel = t >> 7;
    const int c = t & 127;
    const float* srow = single + i * 256;
    const float* w = fW1 + sel * 256 * 128 + c;
    float acc = 0.f;
    for (int k = 0; k < 256; ++k) acc += srow[k] * w[k * 128];
    if (sel == 0) acc += fb1[c];
    float* dst = sel ? pj : pi;
    dst[i * 128 + c] = acc;
}

// ------- kernel 2: fused FiLM -> gamma/beta -> reduction MLP (bf16 MFMA) ----
// block: one i, 128 j's = 4 pipelined tiles of 32; prefetch next tile's
// pj/pair global loads before the current tile's barriers (lgkm-only).
__global__ __launch_bounds__(256) void k_film_red_mfma(
    const float* __restrict__ pair,  // [512][512][128]
    const float* __restrict__ pi,    // [512][128] (includes fb1)
    const float* __restrict__ pj,    // [512][128]
    const u16*   __restrict__ W2T,   // [256][128] bf16
    const float* __restrict__ fb2,   // [256]
    const u16*   __restrict__ rW1T,  // [64][128] bf16
    const float* __restrict__ rb1,   // [64]
    const u16*   __restrict__ rW2T,  // [32][64] bf16
    const float* __restrict__ rb2,   // [32]
    u16* __restrict__ out)           // [512][512][32] bf16
{
    __shared__ __align__(16) char hs [32 * 256];
    __shared__ __align__(16) char p2s[32 * 256];
    __shared__ __align__(16) char t1s[32 * 128];

    const int t = threadIdx.x;
    const int lane = t & 63, w = t >> 6;
    const int g = lane >> 4, ln = lane & 15;
    const int i = blockIdx.x >> 2;
    const int jbase = (blockIdx.x & 3) * 128;
    const int jj = t >> 3, k0 = (t & 7) * 16;
    const int mt3 = w >> 1, nt3 = w & 1;

    // ---- persistent: pi row, all weight fragments, biases ----
    f32x4 pv[4];
    {
        const float* pir = pi + i * 128 + k0;
#pragma unroll
        for (int q4 = 0; q4 < 4; ++q4) pv[q4] = *(const f32x4*)(pir + 4 * q4);
    }
    u16x8 af1[4][4];
#pragma unroll
    for (int a = 0; a < 4; ++a)
#pragma unroll
        for (int ks = 0; ks < 4; ++ks)
            af1[a][ks] = *(const u16x8*)(W2T + ((w + 4 * a) * 16 + ln) * 128 + ks * 32 + g * 8);
    u16x8 af2[4];
#pragma unroll
    for (int ks = 0; ks < 4; ++ks)
        af2[ks] = *(const u16x8*)(rW1T + (w * 16 + ln) * 128 + ks * 32 + g * 8);
    u16x8 a3[2];
#pragma unroll
    for (int ks = 0; ks < 2; ++ks)
        a3[ks] = *(const u16x8*)(rW2T + (mt3 * 16 + ln) * 64 + ks * 32 + g * 8);
    f32x4 blo2[2], bhi2[2];
#pragma unroll
    for (int a2 = 0; a2 < 2; ++a2) {
        const int c0 = (w + 4 * a2) * 16 + g * 4;
        blo2[a2] = *(const f32x4*)(fb2 + c0);
        bhi2[a2] = *(const f32x4*)(fb2 + 128 + c0);
    }
    const f32x4 rbv  = *(const f32x4*)(rb1 + w * 16 + g * 4);
    const f32x4 rb2v = *(const f32x4*)(rb2 + mt3 * 16 + g * 4);

    auto loadQ = [&](int J0, f32x4 (&QV)[4]) {
        const float* pjr = pj + (long)(J0 + jj) * 128 + k0;
#pragma unroll
        for (int q4 = 0; q4 < 4; ++q4) QV[q4] = *(const f32x4*)(pjr + 4 * q4);
    };
    auto loadP = [&](int J0, f32x4 (&PR)[2][2]) {
#pragma unroll
        for (int a2 = 0; a2 < 2; ++a2)
#pragma unroll
            for (int nt = 0; nt < 2; ++nt)
                PR[a2][nt] = *(const f32x4*)(pair + ((long)(i * 512 + J0 + nt * 16 + ln)) * 128
                                             + (w + 4 * a2) * 16 + g * 4);
    };

    auto tile = [&](int J0, f32x4 (&QV)[4], f32x4 (&PR)[2][2],
                    int JN, f32x4 (&QN)[4], f32x4 (&PN)[2][2], bool pref) {
        // h = relu(pi'+pj) -> swizzled LDS bf16
        {
            u16x8 pk0, pk1;
#pragma unroll
            for (int e = 0; e < 8; ++e) {
                const float v0 = pv[e >> 2][e & 3] + QV[e >> 2][e & 3];
                const float v1 = pv[2 + (e >> 2)][e & 3] + QV[2 + (e >> 2)][e & 3];
                pk0[e] = f2bf(fmaxf(v0, 0.f));
                pk1[e] = f2bf(fmaxf(v1, 0.f));
            }
            const int sw = (jj & 7) << 4;
            *(u16x8*)(hs + jj * 256 + ((2 * k0) ^ sw)) = pk0;
            *(u16x8*)(hs + jj * 256 + ((2 * (k0 + 8)) ^ sw)) = pk1;
        }
        if (pref) { loadQ(JN, QN); loadP(JN, PN); }  // ride across barriers
        BARRIER();

        // GEMM1: x[c][j] = W2T[c][:] . h[j][:]
        f32x4 acc[4][2] = {};
#pragma unroll
        for (int ks = 0; ks < 4; ++ks) {
            const int k = ks * 32 + g * 8;
            const int jA = ln, jB = 16 + ln;
            const u16x8 b0 = *(const u16x8*)(hs + jA * 256 + ((2 * k) ^ ((jA & 7) << 4)));
            const u16x8 b1 = *(const u16x8*)(hs + jB * 256 + ((2 * k) ^ ((jB & 7) << 4)));
#pragma unroll
            for (int a = 0; a < 4; ++a) {
                acc[a][0] = MFMA16(af1[a][ks], b0, acc[a][0]);
                acc[a][1] = MFMA16(af1[a][ks], b1, acc[a][1]);
            }
        }

        // modulation: gamma/beta -> p2s
#pragma unroll
        for (int a2 = 0; a2 < 2; ++a2) {
            const int c0 = (w + 4 * a2) * 16 + g * 4;
#pragma unroll
            for (int nt = 0; nt < 2; ++nt) {
                u16x4 pb;
#pragma unroll
                for (int r = 0; r < 4; ++r) {
                    const float xlo = acc[a2][nt][r] + blo2[a2][r];
                    const float xhi = acc[a2 + 2][nt][r] + bhi2[a2][r];
                    const float gam = 1.f + 0.2f * ftanh(xlo);
                    const float bet = 0.2f * ftanh(xhi);
                    pb[r] = f2bf(gam * PR[a2][nt][r] + bet);
                }
                const int j = nt * 16 + ln;
                *(u16x4*)(p2s + j * 256 + ((2 * c0) ^ ((j & 7) << 4))) = pb;
            }
        }
        BARRIER();

        // GEMM2 + gelu -> t1s
        f32x4 acc2[2] = {};
#pragma unroll
        for (int ks = 0; ks < 4; ++ks) {
            const int k = ks * 32 + g * 8;
            const int jA = ln, jB = 16 + ln;
            const u16x8 b0 = *(const u16x8*)(p2s + jA * 256 + ((2 * k) ^ ((jA & 7) << 4)));
            const u16x8 b1 = *(const u16x8*)(p2s + jB * 256 + ((2 * k) ^ ((jB & 7) << 4)));
            acc2[0] = MFMA16(af2[ks], b0, acc2[0]);
            acc2[1] = MFMA16(af2[ks], b1, acc2[1]);
        }
        {
            const int d0 = w * 16 + g * 4;
#pragma unroll
            for (int nt = 0; nt < 2; ++nt) {
                u16x4 tb;
#pragma unroll
                for (int r = 0; r < 4; ++r)
                    tb[r] = f2bf(fgelu(acc2[nt][r] + rbv[r]));
                const int j = nt * 16 + ln;
                *(u16x4*)(t1s + j * 128 + ((2 * d0) ^ ((j & 7) << 4))) = tb;
            }
        }
        BARRIER();

        // GEMM3 -> bf16 store
        {
            f32x4 acc3 = {};
#pragma unroll
            for (int ks = 0; ks < 2; ++ks) {
                const int j = nt3 * 16 + ln;
                const int k = ks * 32 + g * 8;
                const u16x8 b3 = *(const u16x8*)(t1s + j * 128 + ((2 * k) ^ ((j & 7) << 4)));
                acc3 = MFMA16(a3[ks], b3, acc3);
            }
            const int e0 = mt3 * 16 + g * 4;
            u16x4 o;
#pragma unroll
            for (int r = 0; r < 4; ++r) o[r] = f2bf(acc3[r] + rb2v[r]);
            const int j = nt3 * 16 + ln;
            *(u16x4*)(out + ((long)(i * 512 + J0 + j)) * 32 + e0) = o;
        }
    };

    f32x4 qvA[4], qvB[4], prA[2][2], prB[2][2];
    loadQ(jbase, qvA); loadP(jbase, prA);
    tile(jbase,      qvA, prA, jbase + 32, qvB, prB, true);
    tile(jbase + 32, qvB, prB, jbase + 64, qvA, prA, true);
    tile(jbase + 64, qvA, prA, jbase + 96, qvB, prB, true);
    tile(jbase + 96, qvB, prB, jbase,      qvA, prA, false);
}

// ------- kernel 3: windowed MHSA, bf16 I/O, 2 windows / 256-thread block ----
// wave -> (wnd = w>>1, sub = w&1); sub = qkv-part in proj, head in core.
__global__ __launch_bounds__(256) void k_attn_mfma(
    const u16* __restrict__ in, u16* __restrict__ outbuf,
    const u16* __restrict__ qWT,   // [96][32] bf16
    const float* __restrict__ qb,  // [96]
    const u16* __restrict__ oWT,   // [32][32] bf16
    const float* __restrict__ ob,  // [32]
    const int col_pass)
{
    __shared__ __align__(16) char smem[18432 + 9216 + 10240];
    u16 (*qks)[64][72]     = (u16(*)[64][72])smem;             // [2][64][72] q|k
    u16 (*vPs)[2][16][72]  = (u16(*)[2][16][72])(smem + 18432);// [2][2][16][72]
    u16 (*osb)[64][40]     = (u16(*)[64][40])(smem + 27648);   // [2][64][40]
    u16 (*fout)[64][40]    = (u16(*)[64][40])smem;             // overlays qks

    const int t = threadIdx.x;
    const int lane = t & 63, w = t >> 6;
    const int g = lane >> 4, ln = lane & 15;
    const int wnd = w >> 1, sub = w & 1;

    const int wid0 = blockIdx.x * 2;
    long base0, base1; int stride;
    if (col_pass) {
        stride = 512 * 32;
        base0 = (long)((wid0 & 7) * 64) * (512 * 32) + (long)(wid0 >> 3) * 32;
        base1 = (long)(((wid0 + 1) & 7) * 64) * (512 * 32) + (long)((wid0 + 1) >> 3) * 32;
    } else {
        stride = 32;
        base0 = ((long)(wid0 >> 3) * 512 + (wid0 & 7) * 64) * 32;
        base1 = ((long)((wid0 + 1) >> 3) * 512 + ((wid0 + 1) & 7) * 64) * 32;
    }
    const long myb = wnd ? base1 : base0;

    // ---- weights / biases (issue early, L2-hot) ----
    u16x8 bw[4];
#pragma unroll
    for (int nt = 0; nt < 4; ++nt)
        bw[nt] = *(const u16x8*)(qWT + (nt * 16 + ln) * 32 + g * 8);
    const u16x8 av = *(const u16x8*)(qWT + (64 + sub * 16 + ln) * 32 + g * 8);
    u16x8 bo[2];
#pragma unroll
    for (int nt = 0; nt < 2; ++nt)
        bo[nt] = *(const u16x8*)(oWT + (nt * 16 + ln) * 32 + g * 8);
    float qbias[4];
#pragma unroll
    for (int nt = 0; nt < 4; ++nt) qbias[nt] = qb[nt * 16 + ln];
    const f32x4 vb = *(const f32x4*)(qb + 64 + sub * 16 + g * 4);
    float ob2[2];
#pragma unroll
    for (int nt = 0; nt < 2; ++nt) ob2[nt] = ob[nt * 16 + ln];

    // ---- X fragments direct from global (bf16) ----
    u16x8 bx[4];
#pragma unroll
    for (int nt = 0; nt < 4; ++nt)
        bx[nt] = *(const u16x8*)(in + myb + (long)(nt * 16 + ln) * stride + g * 8);

    // ---- projection (wave part p = sub) ----
    {
        const int p = sub;
#pragma unroll
        for (int s = 0; s < 2; ++s) {
            const u16x8 ax = bx[2 * p + s];
            f32x4 qa[4] = {};
#pragma unroll
            for (int nt = 0; nt < 4; ++nt)
                qa[nt] = MFMA16(ax, bw[nt], qa[nt]);
#pragma unroll
            for (int nt = 0; nt < 4; ++nt)
#pragma unroll
                for (int r = 0; r < 4; ++r)
                    qks[wnd][(2 * p + s) * 16 + g * 4 + r][nt * 16 + ln] = f2bf(qa[nt][r] + qbias[nt]);
        }
#pragma unroll
        for (int nt = 0; nt < 4; ++nt) {
            f32x4 va = MFMA16(av, bx[nt], ((f32x4){0.f, 0.f, 0.f, 0.f}));
            const int tok = nt * 16 + ln;
            const int kk = (tok & 32) | ((tok & 12) << 1) | ((tok & 16) >> 2) | (tok & 3);
#pragma unroll
            for (int r = 0; r < 4; ++r)
                vPs[wnd][p][g * 4 + r][kk] = f2bf(va[r] + vb[r]);
        }
    }
    BARRIER();

    // ---- attention core (wave head h = sub), two query-halves -------------
    {
        const int h = sub;
        const u16x8 zero8 = {};
        u16x8 bv[2];
#pragma unroll
        for (int s2 = 0; s2 < 2; ++s2)
            bv[s2] = *(const u16x8*)&vPs[wnd][h][ln][s2 * 32 + g * 8];
#pragma unroll
        for (int half = 0; half < 2; ++half) {
            u16x8 bq[2];
#pragma unroll
            for (int q2 = 0; q2 < 2; ++q2) {
                const int nt = half * 2 + q2;
                bq[q2] = (g < 2) ? *(const u16x8*)&qks[wnd][nt * 16 + ln][h * 16 + g * 8] : zero8;
            }
            f32x4 s_[4][2] = {};
#pragma unroll
            for (int mt = 0; mt < 4; ++mt) {
                const u16x8 ak = (g < 2) ? *(const u16x8*)&qks[wnd][mt * 16 + ln][32 + h * 16 + g * 8] : zero8;
#pragma unroll
                for (int q2 = 0; q2 < 2; ++q2)
                    s_[mt][q2] = MFMA16(ak, bq[q2], s_[mt][q2]);  // S^T[k][q]
            }
#pragma unroll
            for (int q2 = 0; q2 < 2; ++q2) {
                float mx = -1e30f;
#pragma unroll
                for (int mt = 0; mt < 4; ++mt)
#pragma unroll
                    for (int r = 0; r < 4; ++r) {
                        s_[mt][q2][r] *= 0.25f;
                        mx = fmaxf(mx, s_[mt][q2][r]);
                    }
                mx = fmaxf(mx, __shfl_xor(mx, 16));
                mx = fmaxf(mx, __shfl_xor(mx, 32));
                float sum = 0.f;
#pragma unroll
                for (int mt = 0; mt < 4; ++mt)
#pragma unroll
                    for (int r = 0; r < 4; ++r) {
                        const float e_ = __expf(s_[mt][q2][r] - mx);
                        s_[mt][q2][r] = e_;
                        sum += e_;
                    }
                sum += __shfl_xor(sum, 16);
                sum += __shfl_xor(sum, 32);
                const float inv = __builtin_amdgcn_rcpf(sum);
                f32x4 oacc = {};
#pragma unroll
                for (int s2 = 0; s2 < 2; ++s2) {
                    u16x8 pk;
#pragma unroll
                    for (int e = 0; e < 8; ++e)
                        pk[e] = f2bf(s_[2 * s2 + (e >> 2)][q2][e & 3] * inv);
                    oacc = MFMA16(pk, bv[s2], oacc);
                }
                const int ntg = half * 2 + q2;
#pragma unroll
                for (int r = 0; r < 4; ++r)
                    osb[wnd][ntg * 16 + g * 4 + r][h * 16 + ln] = f2bf(oacc[r]);
            }
        }
    }
    BARRIER();

    // ---- out projection -> fout (LDS) ----
    {
        const int p = sub;
#pragma unroll
        for (int s = 0; s < 2; ++s) {
            const u16x8 ao = *(const u16x8*)&osb[wnd][(2 * p + s) * 16 + ln][g * 8];
            f32x4 oa[2] = {};
#pragma unroll
            for (int nt = 0; nt < 2; ++nt)
                oa[nt] = MFMA16(ao, bo[nt], oa[nt]);
#pragma unroll
            for (int nt = 0; nt < 2; ++nt)
#pragma unroll
                for (int r = 0; r < 4; ++r)
                    fout[wnd][(2 * p + s) * 16 + g * 4 + r][nt * 16 + ln] = f2bf(oa[nt][r] + ob2[nt]);
        }
    }
    BARRIER();

    // ---- coalesced bf16 store (full 64B lines) ----
    {
        const int wnd2 = t >> 7, rr = t & 127, tok = rr >> 1, hf = rr & 1;
        const long b2 = wnd2 ? base1 : base0;
        const u16x8 v0 = *(const u16x8*)&fout[wnd2][tok][hf * 16];
        const u16x8 v1 = *(const u16x8*)&fout[wnd2][tok][hf * 16 + 8];
        u16* dst = outbuf + b2 + (long)tok * stride + hf * 16;
        *(u16x8*)dst = v0;
        *(u16x8*)(dst + 8) = v1;
    }
}

// ---------------- kernel 4: head MLP + sigmoid (MFMA) -----------------------
__global__ __launch_bounds__(256) void k_head_mfma(
    const u16* __restrict__ p3,     // [512*512][32] bf16
    const u16* __restrict__ hW1T,   // [64][32] bf16
    const float* __restrict__ hb1,  // [64]
    const float* __restrict__ hW2,  // [64]
    const float* __restrict__ hb2,  // [1]
    float* __restrict__ outp)       // [512*512]
{
    const int t = threadIdx.x, lane = t & 63, w = t >> 6;
    const int g = lane >> 4, ln = lane & 15;
    u16x8 aH[4]; f32x4 b1v[4], w2v[4];
#pragma unroll
    for (int mt = 0; mt < 4; ++mt) {
        aH[mt]  = *(const u16x8*)(hW1T + (mt * 16 + ln) * 32 + g * 8);
        b1v[mt] = *(const f32x4*)(hb1 + mt * 16 + g * 4);
        w2v[mt] = *(const f32x4*)(hW2 + mt * 16 + g * 4);
    }
    const float hb2v = hb2[0];
    const long tok0 = (long)blockIdx.x * 256 + w * 64;
#pragma unroll
    for (int it = 0; it < 4; ++it) {
        const long tb = tok0 + it * 16;
        const u16x8 bxh = *(const u16x8*)(p3 + (tb + ln) * 32 + g * 8);
        float partial = 0.f;
#pragma unroll
        for (int mt = 0; mt < 4; ++mt) {
            f32x4 y = MFMA16(aH[mt], bxh, ((f32x4){0.f, 0.f, 0.f, 0.f}));
#pragma unroll
            for (int r = 0; r < 4; ++r) {
                const float v = fmaxf(y[r] + b1v[mt][r], 0.f);
                partial += v * w2v[mt][r];
            }
        }
        partial += __shfl_xor(partial, 16);
        partial += __shfl_xor(partial, 32);
        if (g == 0) {
            const float logit = partial + hb2v;
            outp[tb + ln] = __builtin_amdgcn_rcpf(1.f + __expf(-logit));
        }
    }
}

// ---------------------------------------------------------------------------
extern "C" void kernel_launch(void* const* d_in, const int* in_sizes, int n_in,
                              void* d_out, int out_size, void* d_ws, size_t ws_size,
                              hipStream_t stream) {
    (void)in_sizes; (void)n_in; (void)out_size; (void)ws_size;
    const float* single = (const float*)d_in[0];
    const float* pair   = (const float*)d_in[1];
    const float* fW1 = (const float*)d_in[2];
    const float* fb1 = (const float*)d_in[3];
    const float* fW2 = (const float*)d_in[4];
    const float* fb2 = (const float*)d_in[5];
    const float* rW1 = (const float*)d_in[6];
    const float* rb1 = (const float*)d_in[7];
    const float* rW2 = (const float*)d_in[8];
    const float* rb2 = (const float*)d_in[9];
    const float* qW  = (const float*)d_in[10];
    const float* qb  = (const float*)d_in[11];
    const float* oW  = (const float*)d_in[12];
    const float* ob  = (const float*)d_in[13];
    const float* hW1 = (const float*)d_in[14];
    const float* hb1 = (const float*)d_in[15];
    const float* hW2 = (const float*)d_in[16];
    const float* hb2 = (const float*)d_in[17];
    float* outp = (float*)d_out;

    char* ws = (char*)d_ws;
    float* pi    = (float*)ws;                          // 256 KB
    float* pj    = (float*)(ws + 256 * 1024);           // 256 KB
    u16*   W2T   = (u16*)(ws + 512 * 1024);             // 64 KB
    u16*   rW1T  = (u16*)(ws + 576 * 1024);             // 16 KB
    u16*   rW2T  = (u16*)(ws + 592 * 1024);             // 4 KB
    u16*   qWTd  = (u16*)(ws + 608 * 1024);             // 6 KB
    u16*   oWTd  = (u16*)(ws + 616 * 1024);             // 2 KB
    u16*   hW1Td = (u16*)(ws + 620 * 1024);             // 4 KB
    u16*   bufA  = (u16*)(ws + 1024 * 1024);            // 16.8 MB
    u16*   bufB  = (u16*)(ws + 1024 * 1024 + 17 * 1024 * 1024);

    k_prep<<<192, 256, 0, stream>>>(fW2, rW1, rW2, qW, oW, hW1,
                                    W2T, rW1T, rW2T, qWTd, oWTd, hW1Td);
    k_pipj<<<512, 256, 0, stream>>>(single, fW1, fb1, pi, pj);
    k_film_red_mfma<<<2048, 256, 0, stream>>>(pair, pi, pj, W2T, fb2,
                                              rW1T, rb1, rW2T, rb2, bufA);
    k_attn_mfma<<<2048, 256, 0, stream>>>(bufA, bufB, qWTd, qb, oWTd, ob, 0);
    k_attn_mfma<<<2048, 256, 0, stream>>>(bufB, bufA, qWTd, qb, oWTd, ob, 1);
    k_head_mfma<<<1024, 256, 0, stream>>>(bufA, hW1Td, hb1, hW2, hb2, outp);
}